// Round 15
// baseline (153.340 us; speedup 1.0000x reference)
//
#include <hip/hip_runtime.h>
#include <cstdint>
#include <cstddef>

using u16 = unsigned short;
using u32 = unsigned int;

typedef __attribute__((ext_vector_type(8))) short short8;  // 8 bf16 (4 VGPRs) MFMA operand
typedef __attribute__((ext_vector_type(4))) float f32x4;   // MFMA accumulator

#define MFMA16(a, b, c) __builtin_amdgcn_mfma_f32_16x16x32_bf16((a), (b), (c), 0, 0, 0)

// folded into Winb/bias1f: D^-0.5 * log2(e)  (softmax in exp2 domain, fixed max 0)
#define QSCALE 0.0450842200f

// RNE f32 -> bf16
__device__ __forceinline__ u16 f2bf(float f) {
  u32 u = __float_as_uint(f);
  return (u16)((u + 0x7FFFu + ((u >> 16) & 1u)) >> 16);
}

__device__ __forceinline__ float bf2f(u32 lo16) {  // low 16 bits = bf16
  return __uint_as_float(lo16 << 16);
}

__device__ __forceinline__ u32 pack_bf16(float a, float b) {
  u32 r;
  asm("v_cvt_pk_bf16_f32 %0, %1, %2" : "=v"(r) : "v"(a), "v"(b));
  return r;
}

// async global->LDS, 16B per lane. lds dest = wave-uniform base + lane*16.
__device__ __forceinline__ void gload_lds16(const u16* g, u16* l) {
  __builtin_amdgcn_global_load_lds((const __attribute__((address_space(1))) void*)g,
                                   (__attribute__((address_space(3))) void*)l, 16, 0, 0);
}

// ---------------- mega-prep: qkv cvt + weight cvt + transposes + bias2 + bias1f ----------------
__global__ __launch_bounds__(256) void prep_all(
    const float* __restrict__ q, const float* __restrict__ k, const float* __restrict__ v,
    const float* __restrict__ Wout_w, const float* __restrict__ Win_w,
    const float* __restrict__ Wff_w, const float* __restrict__ Win_b,
    const float* __restrict__ Wout_b, u16* __restrict__ X,
    u16* __restrict__ Woutb, u16* __restrict__ Winb,
    u16* __restrict__ WinT, u16* __restrict__ WffT,
    float* __restrict__ bias2, float* __restrict__ bias1f) {
  __shared__ float tile[64][68];
  const int t = threadIdx.x;
  const int bid = blockIdx.x;
  if (bid < 12288) {
    int i4 = bid * 256 + t;  // [0, 3145728)
    const float* src = (i4 < 1048576) ? q : (i4 < 2097152) ? k : v;
    int loc = i4 & 1048575;
    float4 w = reinterpret_cast<const float4*>(src)[loc];
    u32 lo = (u32)f2bf(w.x) | ((u32)f2bf(w.y) << 16);
    u32 hi = (u32)f2bf(w.z) | ((u32)f2bf(w.w) << 16);
    reinterpret_cast<uint2*>(X)[i4] = make_uint2(lo, hi);
  } else if (bid < 14336) {
    const int wb = bid - 12288;
    const float* src = wb < 1024 ? Wout_w : Win_w;
    u16* dst = wb < 1024 ? Woutb : Winb;
    const float sc = wb < 1024 ? 1.0f : QSCALE;
    int i = (wb & 1023) * 256 + t;
    float4 vv = reinterpret_cast<const float4*>(src)[i];
    u32 lo = (u32)f2bf(vv.x * sc) | ((u32)f2bf(vv.y * sc) << 16);
    u32 hi = (u32)f2bf(vv.z * sc) | ((u32)f2bf(vv.w * sc) << 16);
    reinterpret_cast<uint2*>(dst)[i] = make_uint2(lo, hi);
  } else if (bid < 14848) {
    const int tb = bid - 14336;
    const float* in = tb < 256 ? Win_w : Wff_w;
    u16* out = tb < 256 ? WinT : WffT;
    const int tix = tb & 255;
    const int bx = (tix >> 4) * 64, by = (tix & 15) * 64;
    const int r = t >> 2, c16 = (t & 3) * 16;
#pragma unroll
    for (int i = 0; i < 4; ++i)
      *reinterpret_cast<float4*>(&tile[r][c16 + i * 4]) =
          *reinterpret_cast<const float4*>(&in[(size_t)(bx + r) * 1024 + by + c16 + i * 4]);
    __syncthreads();
    const int jj = t >> 2, i16 = (t & 3) * 16;
#pragma unroll
    for (int i = 0; i < 4; ++i) {
      uint2 p;
      p.x = (u32)f2bf(tile[i16 + i * 4 + 0][jj]) | ((u32)f2bf(tile[i16 + i * 4 + 1][jj]) << 16);
      p.y = (u32)f2bf(tile[i16 + i * 4 + 2][jj]) | ((u32)f2bf(tile[i16 + i * 4 + 3][jj]) << 16);
      *reinterpret_cast<uint2*>(&out[(size_t)(by + jj) * 1024 + bx + i16 + i * 4]) = p;
    }
  } else if (bid < 15104) {
    const int w = t >> 6, l = t & 63;
    const int j = (bid - 14848) * 4 + w;
    const float4* Wr = reinterpret_cast<const float4*>(Wout_w + (size_t)j * 1024);
    const float4* br = reinterpret_cast<const float4*>(Win_b);
    float s = 0.f;
    for (int i = l; i < 256; i += 64) {
      float4 a = Wr[i], b = br[i];
      s += a.x * b.x + a.y * b.y + a.z * b.z + a.w * b.w;
    }
#pragma unroll
    for (int o = 1; o < 64; o <<= 1) s += __shfl_xor(s, o);
    if (l == 0) bias2[j] = s + Wout_b[j];
  } else {
    float4 vv = reinterpret_cast<const float4*>(Win_b)[t];
    vv.x *= QSCALE; vv.y *= QSCALE; vv.z *= QSCALE; vv.w *= QSCALE;
    reinterpret_cast<float4*>(bias1f)[t] = vv;
  }
}

// ---------------- weight GEMM x2: Cz = A @ Btz^T (1024^3 bf16), dbuf, XCD-swizzled ----------------
__global__ __launch_bounds__(256) void gemm_w2(const u16* __restrict__ A,
                                               const u16* __restrict__ Bt0,
                                               const u16* __restrict__ Bt1,
                                               u16* __restrict__ C0,
                                               u16* __restrict__ C1) {
  const int bid = blockIdx.x;
  const int xcd = bid & 7, local = bid >> 3;    // 64 per XCD
  const int z = local >> 5;                     // 0..1
  const int mt = xcd * 2 + ((local >> 4) & 1);  // 0..15
  const int nt = local & 15;                    // 0..15
  const u16* Bt = z ? Bt1 : Bt0;
  u16* C = z ? C1 : C0;
  __shared__ __align__(16) u16 As[2][4096];
  __shared__ __align__(16) u16 Bs[2][4096];
  const int t = threadIdx.x, w = t >> 6, l = t & 63;
  const int l15 = l & 15, l4 = l >> 4;
  const int m0 = mt * 64, n0 = nt * 64;
  f32x4 acc[4] = {};
  const int row0 = t >> 3, cs0 = t & 7;
  const int c0 = cs0 ^ (row0 & 7);
  const int row1 = row0 + 32;
  const int c1 = cs0 ^ (row1 & 7);
  const u16* gA0 = A + (size_t)(m0 + row0) * 1024 + c0 * 8;
  const u16* gA1 = A + (size_t)(m0 + row1) * 1024 + c1 * 8;
  const u16* gB0 = Bt + (size_t)(n0 + row0) * 1024 + c0 * 8;
  const u16* gB1 = Bt + (size_t)(n0 + row1) * 1024 + c1 * 8;
#define W2_STAGE(KK, DST)                             \
  gload_lds16(gA0 + (KK), &As[DST][0] + w * 512);     \
  gload_lds16(gA1 + (KK), &As[DST][2048] + w * 512);  \
  gload_lds16(gB0 + (KK), &Bs[DST][0] + w * 512);     \
  gload_lds16(gB1 + (KK), &Bs[DST][2048] + w * 512);
  W2_STAGE(0, 0)
  for (int step = 0; step < 16; ++step) {
    const int c = step & 1;
    __syncthreads();
    if (step < 15) { W2_STAGE((step + 1) * 64, c ^ 1) }
#pragma unroll
    for (int ks = 0; ks < 2; ++ks) {
      const int cc = ks * 4 + l4;
      short8 bfr = *reinterpret_cast<const short8*>(&Bs[c][(w * 16 + l15) * 64 + ((cc ^ (l15 & 7)) * 8)]);
#pragma unroll
      for (int i = 0; i < 4; ++i) {
        short8 afr = *reinterpret_cast<const short8*>(&As[c][(i * 16 + l15) * 64 + ((cc ^ (l15 & 7)) * 8)]);
        acc[i] = MFMA16(afr, bfr, acc[i]);
      }
    }
  }
#pragma unroll
  for (int i = 0; i < 4; ++i)
#pragma unroll
    for (int j = 0; j < 4; ++j)
      C[(size_t)(m0 + i * 16 + l4 * 4 + j) * 1024 + n0 + w * 16 + l15] = f2bf(acc[i][j]);
}

// ---------------- fused projection, dbuf, XCD-swizzled (flat 768) — round-12-proven ----------------
__global__ __launch_bounds__(256) void proj(const u16* __restrict__ X,
                                            const u16* __restrict__ Winb,
                                            const u16* __restrict__ Wc2,
                                            const float* __restrict__ bias1f,
                                            const float* __restrict__ bias2,
                                            u16* __restrict__ Qh,
                                            u16* __restrict__ Kp,
                                            u16* __restrict__ VT) {
  __shared__ __align__(16) u16 As[2][4096];
  __shared__ __align__(16) u16 Bs[2][4096];
  const int t = threadIdx.x, w = t >> 6, l = t & 63;
  const int l15 = l & 15, l4 = l >> 4;
  const int bid = blockIdx.x;
  const int xcd = bid & 7, local = bid >> 3;  // 96 per XCD
  const int mt = xcd * 12 + (local >> 3);     // 0..95
  const int nt = local & 7;                   // 0..7
  const int seg = mt >> 5;
  const int m0 = mt * 128;
  const int n0 = nt * 128;
  const int wr = (w >> 1) * 64, wc = (w & 1) * 64;
  const u16* Bt = seg == 0 ? Winb : Wc2;
  const float* bias = seg == 0 ? bias1f : bias2;

  f32x4 acc[4][4] = {};
  const int srow = t >> 2;
  const int sck = (t & 3) ^ ((t >> 3) & 3);
  const u16* gA = X + (size_t)(m0 + srow) * 1024 + sck * 8;
  const u16* gB = Bt + (size_t)(n0 + srow) * 1024 + sck * 8;
#define PJ_STAGE(KK, DST)                                   \
  gload_lds16(gA + (KK), &As[DST][0] + w * 512);            \
  gload_lds16(gA + (KK) + 65536, &As[DST][2048] + w * 512); \
  gload_lds16(gB + (KK), &Bs[DST][0] + w * 512);            \
  gload_lds16(gB + (KK) + 65536, &Bs[DST][2048] + w * 512);
  PJ_STAGE(0, 0)
  const int sw = (l15 >> 1) & 3;  // = (row>>1)&3 for rows wr/wc + i*16 + l15
  for (int step = 0; step < 32; ++step) {
    const int c = step & 1;
    __syncthreads();
    if (step < 31) { PJ_STAGE((step + 1) * 32, c ^ 1) }
    short8 af[4], bf[4];
#pragma unroll
    for (int i = 0; i < 4; ++i)
      af[i] = *reinterpret_cast<const short8*>(&As[c][(wr + i * 16 + l15) * 32 + ((l4 ^ sw) * 8)]);
#pragma unroll
    for (int i = 0; i < 4; ++i)
      bf[i] = *reinterpret_cast<const short8*>(&Bs[c][(wc + i * 16 + l15) * 32 + ((l4 ^ sw) * 8)]);
#pragma unroll
    for (int mi = 0; mi < 4; ++mi)
#pragma unroll
      for (int ni = 0; ni < 4; ++ni)
        acc[mi][ni] = MFMA16(af[mi], bf[ni], acc[mi][ni]);
  }

#pragma unroll
  for (int mi = 0; mi < 4; ++mi) {
#pragma unroll
    for (int ni = 0; ni < 4; ++ni) {
      const int col = n0 + wc + ni * 16 + l15;
      const float bv = bias[col];
      const int row0 = m0 + wr + mi * 16 + l4 * 4;
      if (seg == 0) {
#pragma unroll
        for (int j = 0; j < 4; ++j)
          Qh[(size_t)(row0 + j) * 1024 + col] = f2bf(acc[mi][ni][j] + bv);
      } else if (seg == 1) {
#pragma unroll
        for (int j = 0; j < 4; ++j)
          Kp[(size_t)(row0 - 4096 + j) * 1024 + col] = f2bf(acc[mi][ni][j] + bv);
      } else {
        const int r = row0 - 8192;
        const int bb = r >> 11;
        const int sk = r & 2047;
        u32 p0 = (u32)f2bf(acc[mi][ni][0] + bv) | ((u32)f2bf(acc[mi][ni][1] + bv) << 16);
        u32 p1 = (u32)f2bf(acc[mi][ni][2] + bv) | ((u32)f2bf(acc[mi][ni][3] + bv) << 16);
        *reinterpret_cast<uint2*>(VT + ((size_t)(bb * 1024 + col)) * 2048 + sk) = make_uint2(p0, p1);
      }
    }
  }
}

// ---------------- attention: split-K (2 kh halves) x 4 waves x 32 q-rows ----------------
// flat 1024: bh=(bid&7)*4+((bid>>3)&3); rest=bid>>5: qb=rest&15, kh=rest>>4.
// Swapped QK^T + qg=2 (halved LDS reads per work) + split-K (restores 16 waves/CU).
// LDS 36.9KB -> 4 blocks/CU. Writes bf16 PV partials + f32 row sums (merged by attn_merge).
__global__ __launch_bounds__(256) void attn(const u16* __restrict__ Qh,
                                            const u16* __restrict__ Kb,
                                            const u16* __restrict__ VT,
                                            const int* __restrict__ mask,
                                            u16* __restrict__ PP,
                                            float* __restrict__ S_part) {
  __shared__ __align__(16) u16 Kt[128 * 64];    // [key 0..127][dh], pre-swizzled 16B chunks
  __shared__ __align__(16) u16 Vt[2][64 * 64];  // [half][dh][pos], 128B pitch (2-way free)
  __shared__ float biasS[1024];
  const int t = threadIdx.x, l = t & 63, w = t >> 6;  // w = 0..3
  const int bid = blockIdx.x;
  const int l15 = l & 15, l4 = l >> 4;
  const int bh = (bid & 7) * 4 + ((bid >> 3) & 3);
  const int rest = bid >> 5;
  const int qb = rest & 15, kh = rest >> 4;
  const int b = bh >> 4, h = bh & 15, q0 = qb * 128;
  const int k0g = kh * 1024;

  for (int i = t; i < 1024; i += 256) biasS[i] = mask[b * 2048 + k0g + i] ? 0.f : -1.442695e9f;

  // Q fragments: wave w owns q-rows q0 + w*32 + qg*16 + l15
  short8 qf[2][2];  // [qg][ks]
#pragma unroll
  for (int qg = 0; qg < 2; ++qg) {
    const u16* qp =
        Qh + (size_t)(b * 2048 + q0 + w * 32 + qg * 16 + l15) * 1024 + h * 64 + l4 * 8;
    qf[qg][0] = *reinterpret_cast<const short8*>(qp);
    qf[qg][1] = *reinterpret_cast<const short8*>(qp + 32);
  }
  short8 ones;
#pragma unroll
  for (int i = 0; i < 8; ++i) ones[i] = (short)0x3F80;  // bf16 1.0

  f32x4 acc[2][4] = {};  // [qg][n]
  f32x4 accS[2] = {};    // [qg] partial denominator

  const int rr = t >> 3, cs = t & 7;   // rr 0..31; K rows rr+{0,32,64,96}; V d-rows rr, rr+32
  const int ck = cs ^ (rr & 7);
  const int vb = (ck >> 2) * 32 + (ck & 3) * 4;
  const u16* gK = Kb + (size_t)(b * 2048 + k0g + rr) * 1024 + h * 64 + ck * 8;
  u16* ldsK = Kt + w * 512;
  const u32* gV0 = reinterpret_cast<const u32*>(VT) + (size_t)(b * 1024 + h * 64 + rr) * 1024;
  const u32* gV1 = gV0 + (size_t)32 * 1024;  // d-row rr+32

  for (int kt = 0; kt < 1024; kt += 128) {
    const int ia = ((k0g + kt) >> 1) + (vb >> 1);
    uint2 a01 = *reinterpret_cast<const uint2*>(gV0 + ia);
    uint2 a89 = *reinterpret_cast<const uint2*>(gV0 + ia + 8);
    uint2 b01 = *reinterpret_cast<const uint2*>(gV0 + ia + 32);
    uint2 b89 = *reinterpret_cast<const uint2*>(gV0 + ia + 40);
    uint2 c01 = *reinterpret_cast<const uint2*>(gV1 + ia);
    uint2 c89 = *reinterpret_cast<const uint2*>(gV1 + ia + 8);
    uint2 d01 = *reinterpret_cast<const uint2*>(gV1 + ia + 32);
    uint2 d89 = *reinterpret_cast<const uint2*>(gV1 + ia + 40);
    __syncthreads();  // barrier1: all waves done reading Kt/Vt of previous stage
    gload_lds16(gK + (size_t)kt * 1024, ldsK);
    gload_lds16(gK + (size_t)(kt + 32) * 1024, ldsK + 2048);
    gload_lds16(gK + (size_t)(kt + 64) * 1024, ldsK + 4096);
    gload_lds16(gK + (size_t)(kt + 96) * 1024, ldsK + 6144);
    *reinterpret_cast<uint4*>(&Vt[0][rr * 64 + cs * 8]) = make_uint4(a01.x, a01.y, a89.x, a89.y);
    *reinterpret_cast<uint4*>(&Vt[0][(rr + 32) * 64 + cs * 8]) =
        make_uint4(c01.x, c01.y, c89.x, c89.y);
    *reinterpret_cast<uint4*>(&Vt[1][rr * 64 + cs * 8]) = make_uint4(b01.x, b01.y, b89.x, b89.y);
    *reinterpret_cast<uint4*>(&Vt[1][(rr + 32) * 64 + cs * 8]) =
        make_uint4(d01.x, d01.y, d89.x, d89.y);
    __syncthreads();  // barrier2: staging visible (vmcnt+lgkm drained)

#pragma unroll
    for (int half = 0; half < 2; ++half) {
      const int kb0 = kt + half * 64;
      f32x4 s[4][2];
#pragma unroll
      for (int n = 0; n < 4; ++n) {
        f32x4 bv4 = *reinterpret_cast<const f32x4*>(&biasS[kb0 + n * 16 + l4 * 4]);
        s[n][0] = bv4;
        s[n][1] = bv4;
      }
      __builtin_amdgcn_s_setprio(1);
#pragma unroll
      for (int ks = 0; ks < 2; ++ks) {
        const int cc = ks * 4 + l4;
#pragma unroll
        for (int n = 0; n < 4; ++n) {
          short8 kb = *reinterpret_cast<const short8*>(
              &Kt[(half * 64 + n * 16 + l15) * 64 + ((cc ^ (l15 & 7)) * 8)]);
          s[n][0] = MFMA16(kb, qf[0][ks], s[n][0]);
          s[n][1] = MFMA16(kb, qf[1][ks], s[n][1]);
        }
      }
      __builtin_amdgcn_s_setprio(0);
#pragma unroll
      for (int n = 0; n < 4; ++n)
#pragma unroll
        for (int qg = 0; qg < 2; ++qg)
#pragma unroll
          for (int j = 0; j < 4; ++j) s[n][qg][j] = __builtin_amdgcn_exp2f(s[n][qg][j]);
      short8 pa[2][2];  // [qg][ks]
#pragma unroll
      for (int qg = 0; qg < 2; ++qg) {
        u32 paw[8];
        paw[0] = pack_bf16(s[0][qg][0], s[0][qg][1]);
        paw[1] = pack_bf16(s[0][qg][2], s[0][qg][3]);
        paw[2] = pack_bf16(s[1][qg][0], s[1][qg][1]);
        paw[3] = pack_bf16(s[1][qg][2], s[1][qg][3]);
        paw[4] = pack_bf16(s[2][qg][0], s[2][qg][1]);
        paw[5] = pack_bf16(s[2][qg][2], s[2][qg][3]);
        paw[6] = pack_bf16(s[3][qg][0], s[3][qg][1]);
        paw[7] = pack_bf16(s[3][qg][2], s[3][qg][3]);
        pa[qg][0] = *reinterpret_cast<const short8*>(&paw[0]);
        pa[qg][1] = *reinterpret_cast<const short8*>(&paw[4]);
      }
      __builtin_amdgcn_s_setprio(1);
#pragma unroll
      for (int ks = 0; ks < 2; ++ks) {
        const int cc = ks * 4 + l4;
#pragma unroll
        for (int n = 0; n < 4; ++n) {
          short8 vb8 = *reinterpret_cast<const short8*>(
              &Vt[half][(n * 16 + l15) * 64 + ((cc ^ (l15 & 7)) * 8)]);
          acc[0][n] = MFMA16(pa[0][ks], vb8, acc[0][n]);
          acc[1][n] = MFMA16(pa[1][ks], vb8, acc[1][n]);
        }
        accS[0] = MFMA16(pa[0][ks], ones, accS[0]);
        accS[1] = MFMA16(pa[1][ks], ones, accS[1]);
      }
      __builtin_amdgcn_s_setprio(0);
    }
  }

  // partial epilogue: bf16 PV partials (no divide) + f32 row sums
  u16* PPk = PP + (size_t)kh * 4194304;
#pragma unroll
  for (int qg = 0; qg < 2; ++qg) {
    const size_t orow0 = (size_t)(b * 2048 + q0 + w * 32 + qg * 16 + l4 * 4);
#pragma unroll
    for (int j = 0; j < 4; ++j)
#pragma unroll
      for (int n = 0; n < 4; ++n)
        PPk[(orow0 + j) * 1024 + h * 64 + n * 16 + l15] = f2bf(acc[qg][n][j]);
    if (l15 == 0) {
#pragma unroll
      for (int j = 0; j < 4; ++j) S_part[kh * 4096 + orow0 + j] = accS[qg][j];
    }
  }
}

// ---------------- merge partials -> AO ; plus bias3 = Wout_w@Wff_b + Wout_b ----------------
// bid [0,2048): AO[e] = (PP0[e]+PP1[e]) / (S0[row]+S1[row]); bid [2048,2304): bias3
__global__ __launch_bounds__(256) void attn_merge(const u16* __restrict__ PP,
                                                  const float* __restrict__ S_part,
                                                  const float* __restrict__ Wout_w,
                                                  const float* __restrict__ Wff_b,
                                                  const float* __restrict__ Wout_b,
                                                  u16* __restrict__ AO,
                                                  float* __restrict__ bias3) {
  const int bid = blockIdx.x, t = threadIdx.x;
  if (bid < 2048) {
    const size_t e8 = ((size_t)bid * 256 + t) * 8;
    const int row = (int)(e8 >> 10);
    const float inv = 1.0f / (S_part[row] + S_part[4096 + row]);
    uint4 a = *reinterpret_cast<const uint4*>(PP + e8);
    uint4 c = *reinterpret_cast<const uint4*>(PP + 4194304 + e8);
    u32 aw[4] = {a.x, a.y, a.z, a.w};
    u32 cw[4] = {c.x, c.y, c.z, c.w};
    u32 r[4];
#pragma unroll
    for (int i = 0; i < 4; ++i) {
      float f0 = (bf2f(aw[i] & 0xffffu) + bf2f(cw[i] & 0xffffu)) * inv;
      float f1 = (bf2f(aw[i] >> 16) + bf2f(cw[i] >> 16)) * inv;
      r[i] = pack_bf16(f0, f1);
    }
    *reinterpret_cast<uint4*>(AO + e8) = make_uint4(r[0], r[1], r[2], r[3]);
  } else {
    const int w = t >> 6, l = t & 63;
    const int j = (bid - 2048) * 4 + w;
    const float4* Wr = reinterpret_cast<const float4*>(Wout_w + (size_t)j * 1024);
    const float4* br = reinterpret_cast<const float4*>(Wff_b);
    float s = 0.f;
    for (int i = l; i < 256; i += 64) {
      float4 a = Wr[i], b = br[i];
      s += a.x * b.x + a.y * b.y + a.z * b.z + a.w * b.w;
    }
#pragma unroll
    for (int o = 1; o < 64; o <<= 1) s += __shfl_xor(s, o);
    if (l == 0) bias3[j] = s + Wout_b[j];
  }
}

// ---------------- tail GEMM: out = AO @ Wc3^T + bias3 (f32), dbuf, XCD-swizzled flat 512 ----------------
__global__ __launch_bounds__(256) void gemm_tail(const u16* __restrict__ A,
                                                 const u16* __restrict__ Bt,
                                                 const float* __restrict__ bias,
                                                 float* __restrict__ C) {
  __shared__ __align__(16) u16 As[2][4096];
  __shared__ __align__(16) u16 Bs[2][2048];
  const int t = threadIdx.x, w = t >> 6, l = t & 63;
  const int l15 = l & 15, l4 = l >> 4;
  const int bid = blockIdx.x;
  const int xcd = bid & 7, local = bid >> 3;  // 64 per XCD
  const int mt = xcd * 4 + (local >> 4);      // 0..31
  const int nt = local & 15;                  // 0..15
  const int m0 = mt * 128, n0 = nt * 64;
  const int wr = (w >> 1) * 64, wc = (w & 1) * 32;
  f32x4 acc[4][2] = {};
  const int srow = t >> 2;
  const int sck = (t & 3) ^ ((t >> 3) & 3);
  const u16* gA = A + (size_t)(m0 + srow) * 1024 + sck * 8;
  const u16* gB = Bt + (size_t)(n0 + srow) * 1024 + sck * 8;
#define TL_STAGE(KK, DST)                                   \
  gload_lds16(gA + (KK), &As[DST][0] + w * 512);            \
  gload_lds16(gA + (KK) + 65536, &As[DST][2048] + w * 512); \
  gload_lds16(gB + (KK), &Bs[DST][0] + w * 512);
  TL_STAGE(0, 0)
  const int sw = (l15 >> 1) & 3;
  for (int step = 0; step < 32; ++step) {
    const int c = step & 1;
    __syncthreads();
    if (step < 31) { TL_STAGE((step + 1) * 32, c ^ 1) }
    short8 af[4], bf[2];
#pragma unroll
    for (int i = 0; i < 4; ++i)
      af[i] = *reinterpret_cast<const short8*>(&As[c][(wr + i * 16 + l15) * 32 + ((l4 ^ sw) * 8)]);
#pragma unroll
    for (int i = 0; i < 2; ++i)
      bf[i] = *reinterpret_cast<const short8*>(&Bs[c][(wc + i * 16 + l15) * 32 + ((l4 ^ sw) * 8)]);
#pragma unroll
    for (int mi = 0; mi < 4; ++mi)
#pragma unroll
      for (int ni = 0; ni < 2; ++ni)
        acc[mi][ni] = MFMA16(af[mi], bf[ni], acc[mi][ni]);
  }
#pragma unroll
  for (int mi = 0; mi < 4; ++mi) {
#pragma unroll
    for (int ni = 0; ni < 2; ++ni) {
      const int col = n0 + wc + ni * 16 + l15;
      const float bv = bias[col];
      const int row0 = m0 + wr + mi * 16 + l4 * 4;
#pragma unroll
      for (int j = 0; j < 4; ++j)
        C[(size_t)(row0 + j) * 1024 + col] = acc[mi][ni][j] + bv;
    }
  }
}

// ---------------- launcher ----------------
// ws layout (peak 56,623,104 B, proven):
//   [ 0,24) MB  Xbf (q/k/v bf16 12288x1024); after proj dead ->
//       AO @ [0,8) (written by attn_merge), PP @ [8,24) (kh=0 at 8MB, kh=1 at 16MB)
//   [24,32) MB  Qh ; phase-A tenants WinT@24, Woutb@26, WffT@28; bias3 @ 24MB after attn
//   [32,40) MB  Kproj ; [40,48) VT ; [48,50) Wc2 ; [50,52) Wc3 ; [52,54) Winb
//   d_out scratch (dead until tail): bias2@0, bias1f@1024, S_part@4096..12288
extern "C" void kernel_launch(void* const* d_in, const int* in_sizes, int n_in,
                              void* d_out, int out_size, void* d_ws, size_t ws_size,
                              hipStream_t stream) {
  const float* q = (const float*)d_in[0];
  const float* k = (const float*)d_in[1];
  const float* v = (const float*)d_in[2];
  const float* Win_w = (const float*)d_in[3];
  const float* Win_b = (const float*)d_in[4];
  const float* Wff_w = (const float*)d_in[5];
  const float* Wff_b = (const float*)d_in[6];
  const float* Wout_w = (const float*)d_in[7];
  const float* Wout_b = (const float*)d_in[8];
  const int* mask = (const int*)d_in[9];
  float* out = (float*)d_out;

  char* ws = (char*)d_ws;
  u16* Xbf = (u16*)ws;
  u16* AO = (u16*)ws;
  u16* PP = (u16*)(ws + 8388608);
  u16* Qh = (u16*)(ws + 25165824);
  u16* WinT = (u16*)(ws + 25165824);
  float* bias3 = (float*)(ws + 25165824);  // reuses Qh base after attn
  u16* Woutb = (u16*)(ws + 27262976);
  u16* WffT = (u16*)(ws + 29360128);
  u16* Kproj = (u16*)(ws + 33554432);
  u16* VT = (u16*)(ws + 41943040);
  u16* Wc2 = (u16*)(ws + 50331648);
  u16* Wc3 = (u16*)(ws + 52428800);
  u16* Winb = (u16*)(ws + 54525952);
  float* bias2 = out;
  float* bias1f = out + 1024;
  float* S_part = out + 4096;

  prep_all<<<15105, 256, 0, stream>>>(q, k, v, Wout_w, Win_w, Wff_w, Win_b, Wout_b,
                                      Xbf, Woutb, Winb, WinT, WffT, bias2, bias1f);
  gemm_w2<<<512, 256, 0, stream>>>(Woutb, WinT, WffT, Wc2, Wc3);
  proj<<<768, 256, 0, stream>>>(Xbf, Winb, Wc2, bias1f, bias2, Qh, Kproj, VT);
  attn<<<1024, 256, 0, stream>>>(Qh, Kproj, VT, mask, PP, S_part);
  attn_merge<<<2304, 256, 0, stream>>>(PP, S_part, Wout_w, Wff_b, Wout_b, AO, bias3);
  gemm_tail<<<512, 256, 0, stream>>>(AO, Wc3, bias3, out);
}

// Round 16
// 140.939 us; speedup vs baseline: 1.0880x; 1.0880x over previous
//
#include <hip/hip_runtime.h>
#include <cstdint>
#include <cstddef>

using u16 = unsigned short;
using u32 = unsigned int;

typedef __attribute__((ext_vector_type(8))) short short8;  // 8 bf16 (4 VGPRs) MFMA operand
typedef __attribute__((ext_vector_type(4))) float f32x4;   // MFMA accumulator

#define MFMA16(a, b, c) __builtin_amdgcn_mfma_f32_16x16x32_bf16((a), (b), (c), 0, 0, 0)

// folded into Winb/bias1f: D^-0.5 * log2(e)  (softmax in exp2 domain, fixed max 0)
#define QSCALE 0.0450842200f

// RNE f32 -> bf16
__device__ __forceinline__ u16 f2bf(float f) {
  u32 u = __float_as_uint(f);
  return (u16)((u + 0x7FFFu + ((u >> 16) & 1u)) >> 16);
}

__device__ __forceinline__ u32 pack_bf16(float a, float b) {
  u32 r;
  asm("v_cvt_pk_bf16_f32 %0, %1, %2" : "=v"(r) : "v"(a), "v"(b));
  return r;
}

// async global->LDS, 16B per lane. lds dest = wave-uniform base + lane*16.
__device__ __forceinline__ void gload_lds16(const u16* g, u16* l) {
  __builtin_amdgcn_global_load_lds((const __attribute__((address_space(1))) void*)g,
                                   (__attribute__((address_space(3))) void*)l, 16, 0, 0);
}

// ---------------- mega-prep: qkv cvt + weight cvt + transposes + bias2 + bias1f ----------------
// bid [0,12288):     q,k,v f32 -> Xbf bf16 (rows 0-4095 q, 4096-8191 k, 8192-12287 v)
// bid [12288,13312): Wout_w -> Woutb (bf16)
// bid [13312,14336): Win_w * QSCALE -> Winb (bf16)
// bid [14336,14592): Win_w -> WinT (bf16 transposed, 64x64 tiles)
// bid [14592,14848): Wff_w -> WffT
// bid [14848,15104): bias2[j] = dot(Wout_w[j,:], Win_b) + Wout_b[j]
// bid 15104:         bias1f = Win_b * QSCALE (f32)
__global__ __launch_bounds__(256) void prep_all(
    const float* __restrict__ q, const float* __restrict__ k, const float* __restrict__ v,
    const float* __restrict__ Wout_w, const float* __restrict__ Win_w,
    const float* __restrict__ Wff_w, const float* __restrict__ Win_b,
    const float* __restrict__ Wout_b, u16* __restrict__ X,
    u16* __restrict__ Woutb, u16* __restrict__ Winb,
    u16* __restrict__ WinT, u16* __restrict__ WffT,
    float* __restrict__ bias2, float* __restrict__ bias1f) {
  __shared__ float tile[64][68];
  const int t = threadIdx.x;
  const int bid = blockIdx.x;
  if (bid < 12288) {
    int i4 = bid * 256 + t;  // [0, 3145728)
    const float* src = (i4 < 1048576) ? q : (i4 < 2097152) ? k : v;
    int loc = i4 & 1048575;
    float4 w = reinterpret_cast<const float4*>(src)[loc];
    u32 lo = (u32)f2bf(w.x) | ((u32)f2bf(w.y) << 16);
    u32 hi = (u32)f2bf(w.z) | ((u32)f2bf(w.w) << 16);
    reinterpret_cast<uint2*>(X)[i4] = make_uint2(lo, hi);
  } else if (bid < 14336) {
    const int wb = bid - 12288;
    const float* src = wb < 1024 ? Wout_w : Win_w;
    u16* dst = wb < 1024 ? Woutb : Winb;
    const float sc = wb < 1024 ? 1.0f : QSCALE;
    int i = (wb & 1023) * 256 + t;
    float4 vv = reinterpret_cast<const float4*>(src)[i];
    u32 lo = (u32)f2bf(vv.x * sc) | ((u32)f2bf(vv.y * sc) << 16);
    u32 hi = (u32)f2bf(vv.z * sc) | ((u32)f2bf(vv.w * sc) << 16);
    reinterpret_cast<uint2*>(dst)[i] = make_uint2(lo, hi);
  } else if (bid < 14848) {
    const int tb = bid - 14336;
    const float* in = tb < 256 ? Win_w : Wff_w;
    u16* out = tb < 256 ? WinT : WffT;
    const int tix = tb & 255;
    const int bx = (tix >> 4) * 64, by = (tix & 15) * 64;
    const int r = t >> 2, c16 = (t & 3) * 16;
#pragma unroll
    for (int i = 0; i < 4; ++i)
      *reinterpret_cast<float4*>(&tile[r][c16 + i * 4]) =
          *reinterpret_cast<const float4*>(&in[(size_t)(bx + r) * 1024 + by + c16 + i * 4]);
    __syncthreads();
    const int jj = t >> 2, i16 = (t & 3) * 16;
#pragma unroll
    for (int i = 0; i < 4; ++i) {
      uint2 p;
      p.x = (u32)f2bf(tile[i16 + i * 4 + 0][jj]) | ((u32)f2bf(tile[i16 + i * 4 + 1][jj]) << 16);
      p.y = (u32)f2bf(tile[i16 + i * 4 + 2][jj]) | ((u32)f2bf(tile[i16 + i * 4 + 3][jj]) << 16);
      *reinterpret_cast<uint2*>(&out[(size_t)(by + jj) * 1024 + bx + i16 + i * 4]) = p;
    }
  } else if (bid < 15104) {
    const int w = t >> 6, l = t & 63;
    const int j = (bid - 14848) * 4 + w;
    const float4* Wr = reinterpret_cast<const float4*>(Wout_w + (size_t)j * 1024);
    const float4* br = reinterpret_cast<const float4*>(Win_b);
    float s = 0.f;
    for (int i = l; i < 256; i += 64) {
      float4 a = Wr[i], b = br[i];
      s += a.x * b.x + a.y * b.y + a.z * b.z + a.w * b.w;
    }
#pragma unroll
    for (int o = 1; o < 64; o <<= 1) s += __shfl_xor(s, o);
    if (l == 0) bias2[j] = s + Wout_b[j];
  } else {
    float4 vv = reinterpret_cast<const float4*>(Win_b)[t];
    vv.x *= QSCALE; vv.y *= QSCALE; vv.z *= QSCALE; vv.w *= QSCALE;
    reinterpret_cast<float4*>(bias1f)[t] = vv;
  }
}

// ---------------- weight GEMM x2: Cz = A @ Btz^T (1024^3 bf16), dbuf, XCD-swizzled ----------------
__global__ __launch_bounds__(256) void gemm_w2(const u16* __restrict__ A,
                                               const u16* __restrict__ Bt0,
                                               const u16* __restrict__ Bt1,
                                               u16* __restrict__ C0,
                                               u16* __restrict__ C1) {
  const int bid = blockIdx.x;
  const int xcd = bid & 7, local = bid >> 3;    // 64 per XCD
  const int z = local >> 5;                     // 0..1
  const int mt = xcd * 2 + ((local >> 4) & 1);  // 0..15
  const int nt = local & 15;                    // 0..15
  const u16* Bt = z ? Bt1 : Bt0;
  u16* C = z ? C1 : C0;
  __shared__ __align__(16) u16 As[2][4096];
  __shared__ __align__(16) u16 Bs[2][4096];
  const int t = threadIdx.x, w = t >> 6, l = t & 63;
  const int l15 = l & 15, l4 = l >> 4;
  const int m0 = mt * 64, n0 = nt * 64;
  f32x4 acc[4] = {};
  const int row0 = t >> 3, cs0 = t & 7;
  const int c0 = cs0 ^ (row0 & 7);
  const int row1 = row0 + 32;
  const int c1 = cs0 ^ (row1 & 7);
  const u16* gA0 = A + (size_t)(m0 + row0) * 1024 + c0 * 8;
  const u16* gA1 = A + (size_t)(m0 + row1) * 1024 + c1 * 8;
  const u16* gB0 = Bt + (size_t)(n0 + row0) * 1024 + c0 * 8;
  const u16* gB1 = Bt + (size_t)(n0 + row1) * 1024 + c1 * 8;
#define W2_STAGE(KK, DST)                             \
  gload_lds16(gA0 + (KK), &As[DST][0] + w * 512);     \
  gload_lds16(gA1 + (KK), &As[DST][2048] + w * 512);  \
  gload_lds16(gB0 + (KK), &Bs[DST][0] + w * 512);     \
  gload_lds16(gB1 + (KK), &Bs[DST][2048] + w * 512);
  W2_STAGE(0, 0)
  for (int step = 0; step < 16; ++step) {
    const int c = step & 1;
    __syncthreads();
    if (step < 15) { W2_STAGE((step + 1) * 64, c ^ 1) }
#pragma unroll
    for (int ks = 0; ks < 2; ++ks) {
      const int cc = ks * 4 + l4;
      short8 bfr = *reinterpret_cast<const short8*>(&Bs[c][(w * 16 + l15) * 64 + ((cc ^ (l15 & 7)) * 8)]);
#pragma unroll
      for (int i = 0; i < 4; ++i) {
        short8 afr = *reinterpret_cast<const short8*>(&As[c][(i * 16 + l15) * 64 + ((cc ^ (l15 & 7)) * 8)]);
        acc[i] = MFMA16(afr, bfr, acc[i]);
      }
    }
  }
#pragma unroll
  for (int i = 0; i < 4; ++i)
#pragma unroll
    for (int j = 0; j < 4; ++j)
      C[(size_t)(m0 + i * 16 + l4 * 4 + j) * 1024 + n0 + w * 16 + l15] = f2bf(acc[i][j]);
}

// ---------------- fused projection, dbuf, XCD-swizzled (flat 768) ----------------
// seg = mt>>5: 0: Qh=q@(s*Win)^T+s*Win_b ; 1: Kproj=k@Wc2^T+bias2 ; 2: VT=(v@Wc2^T+bias2)^T
// LDS chunk swizzle: physical chunk cs at row r holds data chunk cs^((r>>1)&3)
// (2-bit XOR involution; read quarter-waves land 2 lanes/bank-quad = conflict-free)
__global__ __launch_bounds__(256) void proj(const u16* __restrict__ X,
                                            const u16* __restrict__ Winb,
                                            const u16* __restrict__ Wc2,
                                            const float* __restrict__ bias1f,
                                            const float* __restrict__ bias2,
                                            u16* __restrict__ Qh,
                                            u16* __restrict__ Kp,
                                            u16* __restrict__ VT) {
  __shared__ __align__(16) u16 As[2][4096];
  __shared__ __align__(16) u16 Bs[2][4096];
  const int t = threadIdx.x, w = t >> 6, l = t & 63;
  const int l15 = l & 15, l4 = l >> 4;
  const int bid = blockIdx.x;
  const int xcd = bid & 7, local = bid >> 3;  // 96 per XCD
  const int mt = xcd * 12 + (local >> 3);     // 0..95
  const int nt = local & 7;                   // 0..7
  const int seg = mt >> 5;
  const int m0 = mt * 128;
  const int n0 = nt * 128;
  const int wr = (w >> 1) * 64, wc = (w & 1) * 64;
  const u16* Bt = seg == 0 ? Winb : Wc2;
  const float* bias = seg == 0 ? bias1f : bias2;

  f32x4 acc[4][4] = {};
  // staging: thread t -> slot (row t>>2, phys chunk t&3); sources data chunk (t&3)^((t>>3)&3).
  // row+64 preserves the swizzle ((row+64)>>1 ≡ row>>1 mod 4), so +65536 reuses the pointer.
  const int srow = t >> 2;
  const int sck = (t & 3) ^ ((t >> 3) & 3);
  const u16* gA = X + (size_t)(m0 + srow) * 1024 + sck * 8;
  const u16* gB = Bt + (size_t)(n0 + srow) * 1024 + sck * 8;
#define PJ_STAGE(KK, DST)                                   \
  gload_lds16(gA + (KK), &As[DST][0] + w * 512);            \
  gload_lds16(gA + (KK) + 65536, &As[DST][2048] + w * 512); \
  gload_lds16(gB + (KK), &Bs[DST][0] + w * 512);            \
  gload_lds16(gB + (KK) + 65536, &Bs[DST][2048] + w * 512);
  PJ_STAGE(0, 0)
  const int sw = (l15 >> 1) & 3;  // = (row>>1)&3 for rows wr/wc + i*16 + l15
  for (int step = 0; step < 32; ++step) {
    const int c = step & 1;
    __syncthreads();
    if (step < 31) { PJ_STAGE((step + 1) * 32, c ^ 1) }
    short8 af[4], bf[4];
#pragma unroll
    for (int i = 0; i < 4; ++i)
      af[i] = *reinterpret_cast<const short8*>(&As[c][(wr + i * 16 + l15) * 32 + ((l4 ^ sw) * 8)]);
#pragma unroll
    for (int i = 0; i < 4; ++i)
      bf[i] = *reinterpret_cast<const short8*>(&Bs[c][(wc + i * 16 + l15) * 32 + ((l4 ^ sw) * 8)]);
#pragma unroll
    for (int mi = 0; mi < 4; ++mi)
#pragma unroll
      for (int ni = 0; ni < 4; ++ni)
        acc[mi][ni] = MFMA16(af[mi], bf[ni], acc[mi][ni]);
  }

#pragma unroll
  for (int mi = 0; mi < 4; ++mi) {
#pragma unroll
    for (int ni = 0; ni < 4; ++ni) {
      const int col = n0 + wc + ni * 16 + l15;
      const float bv = bias[col];
      const int row0 = m0 + wr + mi * 16 + l4 * 4;
      if (seg == 0) {
#pragma unroll
        for (int j = 0; j < 4; ++j)
          Qh[(size_t)(row0 + j) * 1024 + col] = f2bf(acc[mi][ni][j] + bv);
      } else if (seg == 1) {
#pragma unroll
        for (int j = 0; j < 4; ++j)
          Kp[(size_t)(row0 - 4096 + j) * 1024 + col] = f2bf(acc[mi][ni][j] + bv);
      } else {
        const int r = row0 - 8192;
        const int bb = r >> 11;
        const int sk = r & 2047;
        u32 p0 = (u32)f2bf(acc[mi][ni][0] + bv) | ((u32)f2bf(acc[mi][ni][1] + bv) << 16);
        u32 p1 = (u32)f2bf(acc[mi][ni][2] + bv) | ((u32)f2bf(acc[mi][ni][3] + bv) << 16);
        *reinterpret_cast<uint2*>(VT + ((size_t)(bb * 1024 + col)) * 2048 + sk) = make_uint2(p0, p1);
      }
    }
  }
}

// ---------------- fused masked attention: swapped QK^T, in-register P (no P LDS round-trip) ----------------
// flat 640: blocks [0,512) attn (bh=(bid&7)*4+((bid>>3)&3), qb=bid>>5);
//           blocks [512,640) compute bias3 = Wout_w@Wff_b + Wout_b (8 rows/block, 8 waves)
// S^T = MFMA(K,Q) with mask-bias as C-in -> each lane holds P for its own q=l15 column.
// V pos-permutation pos(k): n=k>>4, c=(k&15)>>2, j=k&3 -> pos = (n>>1)*32 + c*8 + (n&1)*4 + j,
// making pa = pack(s[n0],s[n0+1]) feed PV's A-fragment directly (zero cross-lane, zero LDS P).
__global__ __launch_bounds__(512) void attn(const u16* __restrict__ Qh,
                                            const u16* __restrict__ Kb,
                                            const u16* __restrict__ VT,
                                            const int* __restrict__ mask,
                                            u16* __restrict__ AO,
                                            const float* __restrict__ Wout_w,
                                            const float* __restrict__ Wff_b,
                                            const float* __restrict__ Wout_b,
                                            float* __restrict__ bias3) {
  __shared__ __align__(16) u16 Kt[128 * 64];    // [key 0..127][dh], pre-swizzled 16B chunks
  __shared__ __align__(16) u16 Vt[2][64 * 64];  // [half][dh][pos], 128B pitch (2-way free)
  __shared__ float biasS[2048];
  const int t = threadIdx.x, l = t & 63, w = t >> 6;
  const int bid = blockIdx.x;

  if (bid >= 512) {  // bias3 blocks (block-uniform branch)
    const int j = (bid - 512) * 8 + w;
    const float4* Wr = reinterpret_cast<const float4*>(Wout_w + (size_t)j * 1024);
    const float4* br = reinterpret_cast<const float4*>(Wff_b);
    float s = 0.f;
    for (int i = l; i < 256; i += 64) {
      float4 a = Wr[i], b = br[i];
      s += a.x * b.x + a.y * b.y + a.z * b.z + a.w * b.w;
    }
#pragma unroll
    for (int o = 1; o < 64; o <<= 1) s += __shfl_xor(s, o);
    if (l == 0) bias3[j] = s + Wout_b[j];
    return;
  }

  const int l15 = l & 15, l4 = l >> 4;
  const int bh = (bid & 7) * 4 + ((bid >> 3) & 3);
  const int qb = bid >> 5;
  const int b = bh >> 4, h = bh & 15, q0 = qb * 128;

  for (int i = t; i < 2048; i += 512) biasS[i] = mask[b * 2048 + i] ? 0.f : -1.442695e9f;

  short8 qf[2];
  {
    const u16* qp = Qh + (size_t)(b * 2048 + q0 + w * 16 + l15) * 1024 + h * 64 + l4 * 8;
    qf[0] = *reinterpret_cast<const short8*>(qp);
    qf[1] = *reinterpret_cast<const short8*>(qp + 32);
  }
  short8 ones;
#pragma unroll
  for (int i = 0; i < 8; ++i) ones[i] = (short)0x3F80;  // bf16 1.0

  f32x4 acc[4] = {};
  f32x4 accS = {};  // denominator accumulator (every lane ends with its row's sum)

  const int rr = t >> 3, cs = t & 7;   // rr 0..63: K rows rr,rr+64; V d-row rr
  const int ck = cs ^ (rr & 7);        // data chunk stored at this thread's physical slot
  // V gather for new pos order: chunk ck covers keys {vb..vb+3} U {vb+16..vb+19}, vb even
  const int vb = (ck >> 2) * 32 + (ck & 3) * 4;
  const u16* gK = Kb + (size_t)(b * 2048 + rr) * 1024 + h * 64 + ck * 8;
  u16* ldsK = Kt + w * 512;            // wave base; 2nd gload at +4096 (rows 64..127)
  const u32* gVrow = reinterpret_cast<const u32*>(VT) + (size_t)(b * 1024 + h * 64 + rr) * 1024;

  for (int kt = 0; kt < 2048; kt += 128) {
    // V regs for both halves (global, no LDS hazard); keys vb..vb+3 & vb+16..+19 per half
    const int ia = (kt >> 1) + (vb >> 1);
    uint2 a01 = *reinterpret_cast<const uint2*>(gVrow + ia);
    uint2 a89 = *reinterpret_cast<const uint2*>(gVrow + ia + 8);
    uint2 b01 = *reinterpret_cast<const uint2*>(gVrow + ia + 32);
    uint2 b89 = *reinterpret_cast<const uint2*>(gVrow + ia + 40);
    __syncthreads();  // barrier1: all waves done reading Kt/Vt of previous stage
    gload_lds16(gK + (size_t)kt * 1024, ldsK);
    gload_lds16(gK + (size_t)(kt + 64) * 1024, ldsK + 4096);
    *reinterpret_cast<uint4*>(&Vt[0][rr * 64 + cs * 8]) = make_uint4(a01.x, a01.y, a89.x, a89.y);
    *reinterpret_cast<uint4*>(&Vt[1][rr * 64 + cs * 8]) = make_uint4(b01.x, b01.y, b89.x, b89.y);
    __syncthreads();  // barrier2: staging visible (vmcnt+lgkm drained)

#pragma unroll
    for (int half = 0; half < 2; ++half) {
      const int kb0 = kt + half * 64;
      // S^T = bias + K Q^T (bias as MFMA C-in; rows = keys, cols = q)
      f32x4 s[4];
#pragma unroll
      for (int n = 0; n < 4; ++n)
        s[n] = *reinterpret_cast<const f32x4*>(&biasS[kb0 + n * 16 + l4 * 4]);
      __builtin_amdgcn_s_setprio(1);
#pragma unroll
      for (int ks = 0; ks < 2; ++ks) {
        const int cc = ks * 4 + l4;
#pragma unroll
        for (int n = 0; n < 4; ++n) {
          short8 kb = *reinterpret_cast<const short8*>(
              &Kt[(half * 64 + n * 16 + l15) * 64 + ((cc ^ (l15 & 7)) * 8)]);
          s[n] = MFMA16(kb, qf[ks], s[n]);
        }
      }
      __builtin_amdgcn_s_setprio(0);
      // P = exp2(S); lane-local -> pack directly into PV A-fragments
#pragma unroll
      for (int n = 0; n < 4; ++n)
#pragma unroll
        for (int j = 0; j < 4; ++j) s[n][j] = __builtin_amdgcn_exp2f(s[n][j]);
      u32 paw[8];
      paw[0] = pack_bf16(s[0][0], s[0][1]);
      paw[1] = pack_bf16(s[0][2], s[0][3]);
      paw[2] = pack_bf16(s[1][0], s[1][1]);
      paw[3] = pack_bf16(s[1][2], s[1][3]);
      paw[4] = pack_bf16(s[2][0], s[2][1]);
      paw[5] = pack_bf16(s[2][2], s[2][3]);
      paw[6] = pack_bf16(s[3][0], s[3][1]);
      paw[7] = pack_bf16(s[3][2], s[3][3]);
      const short8 pa0 = *reinterpret_cast<const short8*>(&paw[0]);
      const short8 pa1 = *reinterpret_cast<const short8*>(&paw[4]);
      // PV (+ denominator via ones-MFMA)
      __builtin_amdgcn_s_setprio(1);
#pragma unroll
      for (int ks = 0; ks < 2; ++ks) {
        const short8 pa = ks ? pa1 : pa0;
        const int cc = ks * 4 + l4;
#pragma unroll
        for (int n = 0; n < 4; ++n) {
          short8 vb8 = *reinterpret_cast<const short8*>(
              &Vt[half][(n * 16 + l15) * 64 + ((cc ^ (l15 & 7)) * 8)]);
          acc[n] = MFMA16(pa, vb8, acc[n]);
        }
        accS = MFMA16(pa, ones, accS);
      }
      __builtin_amdgcn_s_setprio(0);
    }
  }

  const size_t orow0 = (size_t)(b * 2048 + q0 + w * 16 + l4 * 4);
#pragma unroll
  for (int j = 0; j < 4; ++j) {
    const float inv = 1.0f / accS[j];
#pragma unroll
    for (int n = 0; n < 4; ++n)
      AO[(orow0 + j) * 1024 + h * 64 + n * 16 + l15] = f2bf(acc[n][j] * inv);
  }
}

// ---------------- tail GEMM: out = AO @ Wc3^T + bias3 (f32), dbuf, XCD-swizzled flat 512 ----------------
// Same 2-bit chunk swizzle as proj (conflict-free reads).
__global__ __launch_bounds__(256) void gemm_tail(const u16* __restrict__ A,
                                                 const u16* __restrict__ Bt,
                                                 const float* __restrict__ bias,
                                                 float* __restrict__ C) {
  __shared__ __align__(16) u16 As[2][4096];
  __shared__ __align__(16) u16 Bs[2][2048];
  const int t = threadIdx.x, w = t >> 6, l = t & 63;
  const int l15 = l & 15, l4 = l >> 4;
  const int bid = blockIdx.x;
  const int xcd = bid & 7, local = bid >> 3;  // 64 per XCD
  const int mt = xcd * 4 + (local >> 4);      // 0..31
  const int nt = local & 15;                  // 0..15
  const int m0 = mt * 128, n0 = nt * 64;
  const int wr = (w >> 1) * 64, wc = (w & 1) * 32;
  f32x4 acc[4][2] = {};
  const int srow = t >> 2;
  const int sck = (t & 3) ^ ((t >> 3) & 3);
  const u16* gA = A + (size_t)(m0 + srow) * 1024 + sck * 8;
  const u16* gB = Bt + (size_t)(n0 + srow) * 1024 + sck * 8;
#define TL_STAGE(KK, DST)                                   \
  gload_lds16(gA + (KK), &As[DST][0] + w * 512);            \
  gload_lds16(gA + (KK) + 65536, &As[DST][2048] + w * 512); \
  gload_lds16(gB + (KK), &Bs[DST][0] + w * 512);
  TL_STAGE(0, 0)
  const int sw = (l15 >> 1) & 3;
  for (int step = 0; step < 32; ++step) {
    const int c = step & 1;
    __syncthreads();
    if (step < 31) { TL_STAGE((step + 1) * 32, c ^ 1) }
    short8 af[4], bf[2];
#pragma unroll
    for (int i = 0; i < 4; ++i)
      af[i] = *reinterpret_cast<const short8*>(&As[c][(wr + i * 16 + l15) * 32 + ((l4 ^ sw) * 8)]);
#pragma unroll
    for (int i = 0; i < 2; ++i)
      bf[i] = *reinterpret_cast<const short8*>(&Bs[c][(wc + i * 16 + l15) * 32 + ((l4 ^ sw) * 8)]);
#pragma unroll
    for (int mi = 0; mi < 4; ++mi)
#pragma unroll
      for (int ni = 0; ni < 2; ++ni)
        acc[mi][ni] = MFMA16(af[mi], bf[ni], acc[mi][ni]);
  }
#pragma unroll
  for (int mi = 0; mi < 4; ++mi) {
#pragma unroll
    for (int ni = 0; ni < 2; ++ni) {
      const int col = n0 + wc + ni * 16 + l15;
      const float bv = bias[col];
      const int row0 = m0 + wr + mi * 16 + l4 * 4;
#pragma unroll
      for (int j = 0; j < 4; ++j)
        C[(size_t)(row0 + j) * 1024 + col] = acc[mi][ni][j] + bv;
    }
  }
}

// ---------------- launcher ----------------
// ws layout (peak 56,623,104 B, proven):
//   [ 0,24) MB  Xbf (q/k/v bf16 12288x1024); AO = [0,8) after proj; bias3 @ 20 MB after proj
//   [24,32) MB  Qh ; phase-A tenants: WinT@24, Woutb@26, WffT@28
//   [32,40) MB  Kproj
//   [40,48) MB  VT
//   [48,50) MB  Wc2 ; [50,52) Wc3 ; [52,54) Winb
//   bias2 = d_out[0:1024], bias1f = d_out[1024:2048] (dead until tail overwrites all of out)
extern "C" void kernel_launch(void* const* d_in, const int* in_sizes, int n_in,
                              void* d_out, int out_size, void* d_ws, size_t ws_size,
                              hipStream_t stream) {
  const float* q = (const float*)d_in[0];
  const float* k = (const float*)d_in[1];
  const float* v = (const float*)d_in[2];
  const float* Win_w = (const float*)d_in[3];
  const float* Win_b = (const float*)d_in[4];
  const float* Wff_w = (const float*)d_in[5];
  const float* Wff_b = (const float*)d_in[6];
  const float* Wout_w = (const float*)d_in[7];
  const float* Wout_b = (const float*)d_in[8];
  const int* mask = (const int*)d_in[9];
  float* out = (float*)d_out;

  char* ws = (char*)d_ws;
  u16* Xbf = (u16*)ws;
  u16* AO = (u16*)ws;
  float* bias3 = (float*)(ws + 20971520);
  u16* Qh = (u16*)(ws + 25165824);
  u16* WinT = (u16*)(ws + 25165824);
  u16* Woutb = (u16*)(ws + 27262976);
  u16* WffT = (u16*)(ws + 29360128);
  u16* Kproj = (u16*)(ws + 33554432);
  u16* VT = (u16*)(ws + 41943040);
  u16* Wc2 = (u16*)(ws + 50331648);
  u16* Wc3 = (u16*)(ws + 52428800);
  u16* Winb = (u16*)(ws + 54525952);
  float* bias2 = out;
  float* bias1f = out + 1024;

  prep_all<<<15105, 256, 0, stream>>>(q, k, v, Wout_w, Win_w, Wff_w, Win_b, Wout_b,
                                      Xbf, Woutb, Winb, WinT, WffT, bias2, bias1f);
  gemm_w2<<<512, 256, 0, stream>>>(Woutb, WinT, WffT, Wc2, Wc3);
  proj<<<768, 256, 0, stream>>>(Xbf, Winb, Wc2, bias1f, bias2, Qh, Kproj, VT);
  attn<<<640, 512, 0, stream>>>(Qh, Kproj, VT, mask, AO, Wout_w, Wff_b, Wout_b, bias3);
  gemm_tail<<<512, 256, 0, stream>>>(AO, Wc3, bias3, out);
}

// Round 17
// 137.882 us; speedup vs baseline: 1.1121x; 1.0222x over previous
//
#include <hip/hip_runtime.h>
#include <cstdint>
#include <cstddef>

using u16 = unsigned short;
using u32 = unsigned int;

typedef __attribute__((ext_vector_type(8))) short short8;  // 8 bf16 (4 VGPRs) MFMA operand
typedef __attribute__((ext_vector_type(4))) float f32x4;   // MFMA accumulator

#define MFMA16(a, b, c) __builtin_amdgcn_mfma_f32_16x16x32_bf16((a), (b), (c), 0, 0, 0)

// folded into Winb/bias1f: D^-0.5 * log2(e)  (softmax in exp2 domain, fixed max 0)
#define QSCALE 0.0450842200f

// RNE f32 -> bf16
__device__ __forceinline__ u16 f2bf(float f) {
  u32 u = __float_as_uint(f);
  return (u16)((u + 0x7FFFu + ((u >> 16) & 1u)) >> 16);
}

__device__ __forceinline__ u32 pack_bf16(float a, float b) {
  u32 r;
  asm("v_cvt_pk_bf16_f32 %0, %1, %2" : "=v"(r) : "v"(a), "v"(b));
  return r;
}

// async global->LDS, 16B per lane. lds dest = wave-uniform base + lane*16.
__device__ __forceinline__ void gload_lds16(const u16* g, u16* l) {
  __builtin_amdgcn_global_load_lds((const __attribute__((address_space(1))) void*)g,
                                   (__attribute__((address_space(3))) void*)l, 16, 0, 0);
}

// ---------------- weight prep: cvt + transposes + bias2 + bias1f (2817 blocks) ----------------
// bid [0,1024):    Wout_w -> Woutb (bf16)
// bid [1024,2048): Win_w * QSCALE -> Winb (bf16)
// bid [2048,2304): Win_w -> WinT (bf16 transposed, 64x64 tiles)
// bid [2304,2560): Wff_w -> WffT
// bid [2560,2816): bias2[j] = dot(Wout_w[j,:], Win_b) + Wout_b[j]
// bid 2816:        bias1f = Win_b * QSCALE (f32)
__global__ __launch_bounds__(256) void prep_w(
    const float* __restrict__ Wout_w, const float* __restrict__ Win_w,
    const float* __restrict__ Wff_w, const float* __restrict__ Win_b,
    const float* __restrict__ Wout_b,
    u16* __restrict__ Woutb, u16* __restrict__ Winb,
    u16* __restrict__ WinT, u16* __restrict__ WffT,
    float* __restrict__ bias2, float* __restrict__ bias1f) {
  __shared__ float tile[64][68];
  const int t = threadIdx.x;
  const int bid = blockIdx.x;
  if (bid < 2048) {
    const float* src = bid < 1024 ? Wout_w : Win_w;
    u16* dst = bid < 1024 ? Woutb : Winb;
    const float sc = bid < 1024 ? 1.0f : QSCALE;
    int i = (bid & 1023) * 256 + t;
    float4 vv = reinterpret_cast<const float4*>(src)[i];
    u32 lo = (u32)f2bf(vv.x * sc) | ((u32)f2bf(vv.y * sc) << 16);
    u32 hi = (u32)f2bf(vv.z * sc) | ((u32)f2bf(vv.w * sc) << 16);
    reinterpret_cast<uint2*>(dst)[i] = make_uint2(lo, hi);
  } else if (bid < 2560) {
    const int tb = bid - 2048;
    const float* in = tb < 256 ? Win_w : Wff_w;
    u16* out = tb < 256 ? WinT : WffT;
    const int tix = tb & 255;
    const int bx = (tix >> 4) * 64, by = (tix & 15) * 64;
    const int r = t >> 2, c16 = (t & 3) * 16;
#pragma unroll
    for (int i = 0; i < 4; ++i)
      *reinterpret_cast<float4*>(&tile[r][c16 + i * 4]) =
          *reinterpret_cast<const float4*>(&in[(size_t)(bx + r) * 1024 + by + c16 + i * 4]);
    __syncthreads();
    const int jj = t >> 2, i16 = (t & 3) * 16;
#pragma unroll
    for (int i = 0; i < 4; ++i) {
      uint2 p;
      p.x = (u32)f2bf(tile[i16 + i * 4 + 0][jj]) | ((u32)f2bf(tile[i16 + i * 4 + 1][jj]) << 16);
      p.y = (u32)f2bf(tile[i16 + i * 4 + 2][jj]) | ((u32)f2bf(tile[i16 + i * 4 + 3][jj]) << 16);
      *reinterpret_cast<uint2*>(&out[(size_t)(by + jj) * 1024 + bx + i16 + i * 4]) = p;
    }
  } else if (bid < 2816) {
    const int w = t >> 6, l = t & 63;
    const int j = (bid - 2560) * 4 + w;
    const float4* Wr = reinterpret_cast<const float4*>(Wout_w + (size_t)j * 1024);
    const float4* br = reinterpret_cast<const float4*>(Win_b);
    float s = 0.f;
    for (int i = l; i < 256; i += 64) {
      float4 a = Wr[i], b = br[i];
      s += a.x * b.x + a.y * b.y + a.z * b.z + a.w * b.w;
    }
#pragma unroll
    for (int o = 1; o < 64; o <<= 1) s += __shfl_xor(s, o);
    if (l == 0) bias2[j] = s + Wout_b[j];
  } else {
    float4 vv = reinterpret_cast<const float4*>(Win_b)[t];
    vv.x *= QSCALE; vv.y *= QSCALE; vv.z *= QSCALE; vv.w *= QSCALE;
    reinterpret_cast<float4*>(bias1f)[t] = vv;
  }
}

// ---------------- fused: gemm_w2 (bids 0..511) || qkv cvt (bids 512..12799) ----------------
// Independent segments: gemm_w2 reads prep_w outputs, writes Wc2/Wc3 (compute-bound, 2/CU);
// cvt reads q/k/v f32, writes Xbf (memory-bound). Gemm blocks dispatch first and hide
// under the streaming conversion.
__global__ __launch_bounds__(256) void w2_cvt(const u16* __restrict__ A,
                                              const u16* __restrict__ Bt0,
                                              const u16* __restrict__ Bt1,
                                              u16* __restrict__ C0,
                                              u16* __restrict__ C1,
                                              const float* __restrict__ q,
                                              const float* __restrict__ k,
                                              const float* __restrict__ v,
                                              u16* __restrict__ X) {
  __shared__ __align__(16) u16 As[2][4096];
  __shared__ __align__(16) u16 Bs[2][4096];
  const int bid = blockIdx.x;
  const int t = threadIdx.x;
  if (bid >= 512) {  // qkv conversion segment (block-uniform branch)
    int i4 = (bid - 512) * 256 + t;  // [0, 3145728)
    const float* src = (i4 < 1048576) ? q : (i4 < 2097152) ? k : v;
    int loc = i4 & 1048575;
    float4 w4 = reinterpret_cast<const float4*>(src)[loc];
    u32 lo = (u32)f2bf(w4.x) | ((u32)f2bf(w4.y) << 16);
    u32 hi = (u32)f2bf(w4.z) | ((u32)f2bf(w4.w) << 16);
    reinterpret_cast<uint2*>(X)[i4] = make_uint2(lo, hi);
    return;
  }
  // gemm_w2 segment (round-16-proven body)
  const int xcd = bid & 7, local = bid >> 3;    // 64 per XCD
  const int z = local >> 5;                     // 0..1
  const int mt = xcd * 2 + ((local >> 4) & 1);  // 0..15
  const int nt = local & 15;                    // 0..15
  const u16* Bt = z ? Bt1 : Bt0;
  u16* C = z ? C1 : C0;
  const int w = t >> 6, l = t & 63;
  const int l15 = l & 15, l4 = l >> 4;
  const int m0 = mt * 64, n0 = nt * 64;
  f32x4 acc[4] = {};
  const int row0 = t >> 3, cs0 = t & 7;
  const int c0 = cs0 ^ (row0 & 7);
  const int row1 = row0 + 32;
  const int c1 = cs0 ^ (row1 & 7);
  const u16* gA0 = A + (size_t)(m0 + row0) * 1024 + c0 * 8;
  const u16* gA1 = A + (size_t)(m0 + row1) * 1024 + c1 * 8;
  const u16* gB0 = Bt + (size_t)(n0 + row0) * 1024 + c0 * 8;
  const u16* gB1 = Bt + (size_t)(n0 + row1) * 1024 + c1 * 8;
#define W2_STAGE(KK, DST)                             \
  gload_lds16(gA0 + (KK), &As[DST][0] + w * 512);     \
  gload_lds16(gA1 + (KK), &As[DST][2048] + w * 512);  \
  gload_lds16(gB0 + (KK), &Bs[DST][0] + w * 512);     \
  gload_lds16(gB1 + (KK), &Bs[DST][2048] + w * 512);
  W2_STAGE(0, 0)
  for (int step = 0; step < 16; ++step) {
    const int c = step & 1;
    __syncthreads();
    if (step < 15) { W2_STAGE((step + 1) * 64, c ^ 1) }
#pragma unroll
    for (int ks = 0; ks < 2; ++ks) {
      const int cc = ks * 4 + l4;
      short8 bfr = *reinterpret_cast<const short8*>(&Bs[c][(w * 16 + l15) * 64 + ((cc ^ (l15 & 7)) * 8)]);
#pragma unroll
      for (int i = 0; i < 4; ++i) {
        short8 afr = *reinterpret_cast<const short8*>(&As[c][(i * 16 + l15) * 64 + ((cc ^ (l15 & 7)) * 8)]);
        acc[i] = MFMA16(afr, bfr, acc[i]);
      }
    }
  }
#pragma unroll
  for (int i = 0; i < 4; ++i)
#pragma unroll
    for (int j = 0; j < 4; ++j)
      C[(size_t)(m0 + i * 16 + l4 * 4 + j) * 1024 + n0 + w * 16 + l15] = f2bf(acc[i][j]);
}

// ---------------- fused projection, dbuf, XCD-swizzled (flat 768) ----------------
// seg = mt>>5: 0: Qh=q@(s*Win)^T+s*Win_b ; 1: Kproj=k@Wc2^T+bias2 ; 2: VT=(v@Wc2^T+bias2)^T
// LDS chunk swizzle: physical chunk cs at row r holds data chunk cs^((r>>1)&3)
__global__ __launch_bounds__(256) void proj(const u16* __restrict__ X,
                                            const u16* __restrict__ Winb,
                                            const u16* __restrict__ Wc2,
                                            const float* __restrict__ bias1f,
                                            const float* __restrict__ bias2,
                                            u16* __restrict__ Qh,
                                            u16* __restrict__ Kp,
                                            u16* __restrict__ VT) {
  __shared__ __align__(16) u16 As[2][4096];
  __shared__ __align__(16) u16 Bs[2][4096];
  const int t = threadIdx.x, w = t >> 6, l = t & 63;
  const int l15 = l & 15, l4 = l >> 4;
  const int bid = blockIdx.x;
  const int xcd = bid & 7, local = bid >> 3;  // 96 per XCD
  const int mt = xcd * 12 + (local >> 3);     // 0..95
  const int nt = local & 7;                   // 0..7
  const int seg = mt >> 5;
  const int m0 = mt * 128;
  const int n0 = nt * 128;
  const int wr = (w >> 1) * 64, wc = (w & 1) * 64;
  const u16* Bt = seg == 0 ? Winb : Wc2;
  const float* bias = seg == 0 ? bias1f : bias2;

  f32x4 acc[4][4] = {};
  const int srow = t >> 2;
  const int sck = (t & 3) ^ ((t >> 3) & 3);
  const u16* gA = X + (size_t)(m0 + srow) * 1024 + sck * 8;
  const u16* gB = Bt + (size_t)(n0 + srow) * 1024 + sck * 8;
#define PJ_STAGE(KK, DST)                                   \
  gload_lds16(gA + (KK), &As[DST][0] + w * 512);            \
  gload_lds16(gA + (KK) + 65536, &As[DST][2048] + w * 512); \
  gload_lds16(gB + (KK), &Bs[DST][0] + w * 512);            \
  gload_lds16(gB + (KK) + 65536, &Bs[DST][2048] + w * 512);
  PJ_STAGE(0, 0)
  const int sw = (l15 >> 1) & 3;  // = (row>>1)&3 for rows wr/wc + i*16 + l15
  for (int step = 0; step < 32; ++step) {
    const int c = step & 1;
    __syncthreads();
    if (step < 31) { PJ_STAGE((step + 1) * 32, c ^ 1) }
    short8 af[4], bf[4];
#pragma unroll
    for (int i = 0; i < 4; ++i)
      af[i] = *reinterpret_cast<const short8*>(&As[c][(wr + i * 16 + l15) * 32 + ((l4 ^ sw) * 8)]);
#pragma unroll
    for (int i = 0; i < 4; ++i)
      bf[i] = *reinterpret_cast<const short8*>(&Bs[c][(wc + i * 16 + l15) * 32 + ((l4 ^ sw) * 8)]);
#pragma unroll
    for (int mi = 0; mi < 4; ++mi)
#pragma unroll
      for (int ni = 0; ni < 4; ++ni)
        acc[mi][ni] = MFMA16(af[mi], bf[ni], acc[mi][ni]);
  }

#pragma unroll
  for (int mi = 0; mi < 4; ++mi) {
#pragma unroll
    for (int ni = 0; ni < 4; ++ni) {
      const int col = n0 + wc + ni * 16 + l15;
      const float bv = bias[col];
      const int row0 = m0 + wr + mi * 16 + l4 * 4;
      if (seg == 0) {
#pragma unroll
        for (int j = 0; j < 4; ++j)
          Qh[(size_t)(row0 + j) * 1024 + col] = f2bf(acc[mi][ni][j] + bv);
      } else if (seg == 1) {
#pragma unroll
        for (int j = 0; j < 4; ++j)
          Kp[(size_t)(row0 - 4096 + j) * 1024 + col] = f2bf(acc[mi][ni][j] + bv);
      } else {
        const int r = row0 - 8192;
        const int bb = r >> 11;
        const int sk = r & 2047;
        u32 p0 = (u32)f2bf(acc[mi][ni][0] + bv) | ((u32)f2bf(acc[mi][ni][1] + bv) << 16);
        u32 p1 = (u32)f2bf(acc[mi][ni][2] + bv) | ((u32)f2bf(acc[mi][ni][3] + bv) << 16);
        *reinterpret_cast<uint2*>(VT + ((size_t)(bb * 1024 + col)) * 2048 + sk) = make_uint2(p0, p1);
      }
    }
  }
}

// ---------------- fused masked attention: swapped QK^T, in-register P (round-16-proven) ----------------
// flat 640: blocks [0,512) attn (bh=(bid&7)*4+((bid>>3)&3), qb=bid>>5);
//           blocks [512,640) compute bias3 = Wout_w@Wff_b + Wout_b (8 rows/block, 8 waves)
__global__ __launch_bounds__(512) void attn(const u16* __restrict__ Qh,
                                            const u16* __restrict__ Kb,
                                            const u16* __restrict__ VT,
                                            const int* __restrict__ mask,
                                            u16* __restrict__ AO,
                                            const float* __restrict__ Wout_w,
                                            const float* __restrict__ Wff_b,
                                            const float* __restrict__ Wout_b,
                                            float* __restrict__ bias3) {
  __shared__ __align__(16) u16 Kt[128 * 64];    // [key 0..127][dh], pre-swizzled 16B chunks
  __shared__ __align__(16) u16 Vt[2][64 * 64];  // [half][dh][pos], 128B pitch (2-way free)
  __shared__ float biasS[2048];
  const int t = threadIdx.x, l = t & 63, w = t >> 6;
  const int bid = blockIdx.x;

  if (bid >= 512) {  // bias3 blocks (block-uniform branch)
    const int j = (bid - 512) * 8 + w;
    const float4* Wr = reinterpret_cast<const float4*>(Wout_w + (size_t)j * 1024);
    const float4* br = reinterpret_cast<const float4*>(Wff_b);
    float s = 0.f;
    for (int i = l; i < 256; i += 64) {
      float4 a = Wr[i], b = br[i];
      s += a.x * b.x + a.y * b.y + a.z * b.z + a.w * b.w;
    }
#pragma unroll
    for (int o = 1; o < 64; o <<= 1) s += __shfl_xor(s, o);
    if (l == 0) bias3[j] = s + Wout_b[j];
    return;
  }

  const int l15 = l & 15, l4 = l >> 4;
  const int bh = (bid & 7) * 4 + ((bid >> 3) & 3);
  const int qb = bid >> 5;
  const int b = bh >> 4, h = bh & 15, q0 = qb * 128;

  for (int i = t; i < 2048; i += 512) biasS[i] = mask[b * 2048 + i] ? 0.f : -1.442695e9f;

  short8 qf[2];
  {
    const u16* qp = Qh + (size_t)(b * 2048 + q0 + w * 16 + l15) * 1024 + h * 64 + l4 * 8;
    qf[0] = *reinterpret_cast<const short8*>(qp);
    qf[1] = *reinterpret_cast<const short8*>(qp + 32);
  }
  short8 ones;
#pragma unroll
  for (int i = 0; i < 8; ++i) ones[i] = (short)0x3F80;  // bf16 1.0

  f32x4 acc[4] = {};
  f32x4 accS = {};  // denominator accumulator (every lane ends with its row's sum)

  const int rr = t >> 3, cs = t & 7;   // rr 0..63: K rows rr,rr+64; V d-row rr
  const int ck = cs ^ (rr & 7);        // data chunk stored at this thread's physical slot
  const int vb = (ck >> 2) * 32 + (ck & 3) * 4;
  const u16* gK = Kb + (size_t)(b * 2048 + rr) * 1024 + h * 64 + ck * 8;
  u16* ldsK = Kt + w * 512;            // wave base; 2nd gload at +4096 (rows 64..127)
  const u32* gVrow = reinterpret_cast<const u32*>(VT) + (size_t)(b * 1024 + h * 64 + rr) * 1024;

  for (int kt = 0; kt < 2048; kt += 128) {
    const int ia = (kt >> 1) + (vb >> 1);
    uint2 a01 = *reinterpret_cast<const uint2*>(gVrow + ia);
    uint2 a89 = *reinterpret_cast<const uint2*>(gVrow + ia + 8);
    uint2 b01 = *reinterpret_cast<const uint2*>(gVrow + ia + 32);
    uint2 b89 = *reinterpret_cast<const uint2*>(gVrow + ia + 40);
    __syncthreads();  // barrier1: all waves done reading Kt/Vt of previous stage
    gload_lds16(gK + (size_t)kt * 1024, ldsK);
    gload_lds16(gK + (size_t)(kt + 64) * 1024, ldsK + 4096);
    *reinterpret_cast<uint4*>(&Vt[0][rr * 64 + cs * 8]) = make_uint4(a01.x, a01.y, a89.x, a89.y);
    *reinterpret_cast<uint4*>(&Vt[1][rr * 64 + cs * 8]) = make_uint4(b01.x, b01.y, b89.x, b89.y);
    __syncthreads();  // barrier2: staging visible (vmcnt+lgkm drained)

#pragma unroll
    for (int half = 0; half < 2; ++half) {
      const int kb0 = kt + half * 64;
      f32x4 s[4];
#pragma unroll
      for (int n = 0; n < 4; ++n)
        s[n] = *reinterpret_cast<const f32x4*>(&biasS[kb0 + n * 16 + l4 * 4]);
      __builtin_amdgcn_s_setprio(1);
#pragma unroll
      for (int ks = 0; ks < 2; ++ks) {
        const int cc = ks * 4 + l4;
#pragma unroll
        for (int n = 0; n < 4; ++n) {
          short8 kb = *reinterpret_cast<const short8*>(
              &Kt[(half * 64 + n * 16 + l15) * 64 + ((cc ^ (l15 & 7)) * 8)]);
          s[n] = MFMA16(kb, qf[ks], s[n]);
        }
      }
      __builtin_amdgcn_s_setprio(0);
#pragma unroll
      for (int n = 0; n < 4; ++n)
#pragma unroll
        for (int j = 0; j < 4; ++j) s[n][j] = __builtin_amdgcn_exp2f(s[n][j]);
      u32 paw[8];
      paw[0] = pack_bf16(s[0][0], s[0][1]);
      paw[1] = pack_bf16(s[0][2], s[0][3]);
      paw[2] = pack_bf16(s[1][0], s[1][1]);
      paw[3] = pack_bf16(s[1][2], s[1][3]);
      paw[4] = pack_bf16(s[2][0], s[2][1]);
      paw[5] = pack_bf16(s[2][2], s[2][3]);
      paw[6] = pack_bf16(s[3][0], s[3][1]);
      paw[7] = pack_bf16(s[3][2], s[3][3]);
      const short8 pa0 = *reinterpret_cast<const short8*>(&paw[0]);
      const short8 pa1 = *reinterpret_cast<const short8*>(&paw[4]);
      __builtin_amdgcn_s_setprio(1);
#pragma unroll
      for (int ks = 0; ks < 2; ++ks) {
        const short8 pa = ks ? pa1 : pa0;
        const int cc = ks * 4 + l4;
#pragma unroll
        for (int n = 0; n < 4; ++n) {
          short8 vb8 = *reinterpret_cast<const short8*>(
              &Vt[half][(n * 16 + l15) * 64 + ((cc ^ (l15 & 7)) * 8)]);
          acc[n] = MFMA16(pa, vb8, acc[n]);
        }
        accS = MFMA16(pa, ones, accS);
      }
      __builtin_amdgcn_s_setprio(0);
    }
  }

  const size_t orow0 = (size_t)(b * 2048 + q0 + w * 16 + l4 * 4);
#pragma unroll
  for (int j = 0; j < 4; ++j) {
    const float inv = 1.0f / accS[j];
#pragma unroll
    for (int n = 0; n < 4; ++n)
      AO[(orow0 + j) * 1024 + h * 64 + n * 16 + l15] = f2bf(acc[n][j] * inv);
  }
}

// ---------------- tail GEMM: out = AO @ Wc3^T + bias3 (f32), dbuf, XCD-swizzled flat 512 ----------------
__global__ __launch_bounds__(256) void gemm_tail(const u16* __restrict__ A,
                                                 const u16* __restrict__ Bt,
                                                 const float* __restrict__ bias,
                                                 float* __restrict__ C) {
  __shared__ __align__(16) u16 As[2][4096];
  __shared__ __align__(16) u16 Bs[2][2048];
  const int t = threadIdx.x, w = t >> 6, l = t & 63;
  const int l15 = l & 15, l4 = l >> 4;
  const int bid = blockIdx.x;
  const int xcd = bid & 7, local = bid >> 3;  // 64 per XCD
  const int mt = xcd * 4 + (local >> 4);      // 0..31
  const int nt = local & 15;                  // 0..15
  const int m0 = mt * 128, n0 = nt * 64;
  const int wr = (w >> 1) * 64, wc = (w & 1) * 32;
  f32x4 acc[4][2] = {};
  const int srow = t >> 2;
  const int sck = (t & 3) ^ ((t >> 3) & 3);
  const u16* gA = A + (size_t)(m0 + srow) * 1024 + sck * 8;
  const u16* gB = Bt + (size_t)(n0 + srow) * 1024 + sck * 8;
#define TL_STAGE(KK, DST)                                   \
  gload_lds16(gA + (KK), &As[DST][0] + w * 512);            \
  gload_lds16(gA + (KK) + 65536, &As[DST][2048] + w * 512); \
  gload_lds16(gB + (KK), &Bs[DST][0] + w * 512);
  TL_STAGE(0, 0)
  const int sw = (l15 >> 1) & 3;
  for (int step = 0; step < 32; ++step) {
    const int c = step & 1;
    __syncthreads();
    if (step < 31) { TL_STAGE((step + 1) * 32, c ^ 1) }
    short8 af[4], bf[2];
#pragma unroll
    for (int i = 0; i < 4; ++i)
      af[i] = *reinterpret_cast<const short8*>(&As[c][(wr + i * 16 + l15) * 32 + ((l4 ^ sw) * 8)]);
#pragma unroll
    for (int i = 0; i < 2; ++i)
      bf[i] = *reinterpret_cast<const short8*>(&Bs[c][(wc + i * 16 + l15) * 32 + ((l4 ^ sw) * 8)]);
#pragma unroll
    for (int mi = 0; mi < 4; ++mi)
#pragma unroll
      for (int ni = 0; ni < 2; ++ni)
        acc[mi][ni] = MFMA16(af[mi], bf[ni], acc[mi][ni]);
  }
#pragma unroll
  for (int mi = 0; mi < 4; ++mi) {
#pragma unroll
    for (int ni = 0; ni < 2; ++ni) {
      const int col = n0 + wc + ni * 16 + l15;
      const float bv = bias[col];
      const int row0 = m0 + wr + mi * 16 + l4 * 4;
#pragma unroll
      for (int j = 0; j < 4; ++j)
        C[(size_t)(row0 + j) * 1024 + col] = acc[mi][ni][j] + bv;
    }
  }
}

// ---------------- launcher ----------------
// ws layout (peak 56,623,104 B, proven):
//   [ 0,24) MB  Xbf (q/k/v bf16 12288x1024); AO = [0,8) after proj; bias3 @ 20 MB after proj
//   [24,32) MB  Qh ; phase-A tenants: WinT@24, Woutb@26, WffT@28
//   [32,40) MB  Kproj
//   [40,48) MB  VT
//   [48,50) MB  Wc2 ; [50,52) Wc3 ; [52,54) Winb
//   bias2 = d_out[0:1024], bias1f = d_out[1024:2048] (dead until tail overwrites all of out)
extern "C" void kernel_launch(void* const* d_in, const int* in_sizes, int n_in,
                              void* d_out, int out_size, void* d_ws, size_t ws_size,
                              hipStream_t stream) {
  const float* q = (const float*)d_in[0];
  const float* k = (const float*)d_in[1];
  const float* v = (const float*)d_in[2];
  const float* Win_w = (const float*)d_in[3];
  const float* Win_b = (const float*)d_in[4];
  const float* Wff_w = (const float*)d_in[5];
  const float* Wff_b = (const float*)d_in[6];
  const float* Wout_w = (const float*)d_in[7];
  const float* Wout_b = (const float*)d_in[8];
  const int* mask = (const int*)d_in[9];
  float* out = (float*)d_out;

  char* ws = (char*)d_ws;
  u16* Xbf = (u16*)ws;
  u16* AO = (u16*)ws;
  float* bias3 = (float*)(ws + 20971520);
  u16* Qh = (u16*)(ws + 25165824);
  u16* WinT = (u16*)(ws + 25165824);
  u16* Woutb = (u16*)(ws + 27262976);
  u16* WffT = (u16*)(ws + 29360128);
  u16* Kproj = (u16*)(ws + 33554432);
  u16* VT = (u16*)(ws + 41943040);
  u16* Wc2 = (u16*)(ws + 50331648);
  u16* Wc3 = (u16*)(ws + 52428800);
  u16* Winb = (u16*)(ws + 54525952);
  float* bias2 = out;
  float* bias1f = out + 1024;

  prep_w<<<2817, 256, 0, stream>>>(Wout_w, Win_w, Wff_w, Win_b, Wout_b,
                                   Woutb, Winb, WinT, WffT, bias2, bias1f);
  w2_cvt<<<12800, 256, 0, stream>>>(Woutb, WinT, WffT, Wc2, Wc3, q, k, v, Xbf);
  proj<<<768, 256, 0, stream>>>(Xbf, Winb, Wc2, bias1f, bias2, Qh, Kproj, VT);
  attn<<<640, 512, 0, stream>>>(Qh, Kproj, VT, mask, AO, Wout_w, Wff_b, Wout_b, bias3);
  gemm_tail<<<512, 256, 0, stream>>>(AO, Wc3, bias3, out);
}

// Round 18
// 137.687 us; speedup vs baseline: 1.1137x; 1.0014x over previous
//
#include <hip/hip_runtime.h>
#include <cstdint>
#include <cstddef>

using u16 = unsigned short;
using u32 = unsigned int;

typedef __attribute__((ext_vector_type(8))) short short8;  // 8 bf16 (4 VGPRs) MFMA operand
typedef __attribute__((ext_vector_type(4))) float f32x4;   // MFMA accumulator

#define MFMA16(a, b, c) __builtin_amdgcn_mfma_f32_16x16x32_bf16((a), (b), (c), 0, 0, 0)

// folded into Winb/bias1f: D^-0.5 * log2(e)  (softmax in exp2 domain, fixed max 0)
#define QSCALE 0.0450842200f

// RNE f32 -> bf16
__device__ __forceinline__ u16 f2bf(float f) {
  u32 u = __float_as_uint(f);
  return (u16)((u + 0x7FFFu + ((u >> 16) & 1u)) >> 16);
}

__device__ __forceinline__ u32 pack_bf16(float a, float b) {
  u32 r;
  asm("v_cvt_pk_bf16_f32 %0, %1, %2" : "=v"(r) : "v"(a), "v"(b));
  return r;
}

// async global->LDS, 16B per lane. lds dest = wave-uniform base + lane*16.
__device__ __forceinline__ void gload_lds16(const u16* g, u16* l) {
  __builtin_amdgcn_global_load_lds((const __attribute__((address_space(1))) void*)g,
                                   (__attribute__((address_space(3))) void*)l, 16, 0, 0);
}

// ---------------- weight prep: cvt + transposes + bias2 + bias1f (2817 blocks) ----------------
// bid [0,1024):    Wout_w -> Woutb (bf16)
// bid [1024,2048): Win_w * QSCALE -> Winb (bf16)
// bid [2048,2304): Win_w -> WinT (bf16 transposed, 64x64 tiles)
// bid [2304,2560): Wff_w -> WffT
// bid [2560,2816): bias2[j] = dot(Wout_w[j,:], Win_b) + Wout_b[j]
// bid 2816:        bias1f = Win_b * QSCALE (f32)
__global__ __launch_bounds__(256) void prep_w(
    const float* __restrict__ Wout_w, const float* __restrict__ Win_w,
    const float* __restrict__ Wff_w, const float* __restrict__ Win_b,
    const float* __restrict__ Wout_b,
    u16* __restrict__ Woutb, u16* __restrict__ Winb,
    u16* __restrict__ WinT, u16* __restrict__ WffT,
    float* __restrict__ bias2, float* __restrict__ bias1f) {
  __shared__ float tile[64][68];
  const int t = threadIdx.x;
  const int bid = blockIdx.x;
  if (bid < 2048) {
    const float* src = bid < 1024 ? Wout_w : Win_w;
    u16* dst = bid < 1024 ? Woutb : Winb;
    const float sc = bid < 1024 ? 1.0f : QSCALE;
    int i = (bid & 1023) * 256 + t;
    float4 vv = reinterpret_cast<const float4*>(src)[i];
    u32 lo = (u32)f2bf(vv.x * sc) | ((u32)f2bf(vv.y * sc) << 16);
    u32 hi = (u32)f2bf(vv.z * sc) | ((u32)f2bf(vv.w * sc) << 16);
    reinterpret_cast<uint2*>(dst)[i] = make_uint2(lo, hi);
  } else if (bid < 2560) {
    const int tb = bid - 2048;
    const float* in = tb < 256 ? Win_w : Wff_w;
    u16* out = tb < 256 ? WinT : WffT;
    const int tix = tb & 255;
    const int bx = (tix >> 4) * 64, by = (tix & 15) * 64;
    const int r = t >> 2, c16 = (t & 3) * 16;
#pragma unroll
    for (int i = 0; i < 4; ++i)
      *reinterpret_cast<float4*>(&tile[r][c16 + i * 4]) =
          *reinterpret_cast<const float4*>(&in[(size_t)(bx + r) * 1024 + by + c16 + i * 4]);
    __syncthreads();
    const int jj = t >> 2, i16 = (t & 3) * 16;
#pragma unroll
    for (int i = 0; i < 4; ++i) {
      uint2 p;
      p.x = (u32)f2bf(tile[i16 + i * 4 + 0][jj]) | ((u32)f2bf(tile[i16 + i * 4 + 1][jj]) << 16);
      p.y = (u32)f2bf(tile[i16 + i * 4 + 2][jj]) | ((u32)f2bf(tile[i16 + i * 4 + 3][jj]) << 16);
      *reinterpret_cast<uint2*>(&out[(size_t)(by + jj) * 1024 + bx + i16 + i * 4]) = p;
    }
  } else if (bid < 2816) {
    const int w = t >> 6, l = t & 63;
    const int j = (bid - 2560) * 4 + w;
    const float4* Wr = reinterpret_cast<const float4*>(Wout_w + (size_t)j * 1024);
    const float4* br = reinterpret_cast<const float4*>(Win_b);
    float s = 0.f;
    for (int i = l; i < 256; i += 64) {
      float4 a = Wr[i], b = br[i];
      s += a.x * b.x + a.y * b.y + a.z * b.z + a.w * b.w;
    }
#pragma unroll
    for (int o = 1; o < 64; o <<= 1) s += __shfl_xor(s, o);
    if (l == 0) bias2[j] = s + Wout_b[j];
  } else {
    float4 vv = reinterpret_cast<const float4*>(Win_b)[t];
    vv.x *= QSCALE; vv.y *= QSCALE; vv.z *= QSCALE; vv.w *= QSCALE;
    reinterpret_cast<float4*>(bias1f)[t] = vv;
  }
}

// ---------------- fused: gemm_w2 (bids 0..511) || qkv cvt (bids 512..12799) ----------------
// Independent segments: gemm_w2 reads prep_w outputs, writes Wc2/Wc3 (compute-bound, 2/CU);
// cvt reads q/k/v f32, writes Xbf (memory-bound). Gemm blocks dispatch first and hide
// under the streaming conversion.
__global__ __launch_bounds__(256) void w2_cvt(const u16* __restrict__ A,
                                              const u16* __restrict__ Bt0,
                                              const u16* __restrict__ Bt1,
                                              u16* __restrict__ C0,
                                              u16* __restrict__ C1,
                                              const float* __restrict__ q,
                                              const float* __restrict__ k,
                                              const float* __restrict__ v,
                                              u16* __restrict__ X) {
  __shared__ __align__(16) u16 As[2][4096];
  __shared__ __align__(16) u16 Bs[2][4096];
  const int bid = blockIdx.x;
  const int t = threadIdx.x;
  if (bid >= 512) {  // qkv conversion segment (block-uniform branch)
    int i4 = (bid - 512) * 256 + t;  // [0, 3145728)
    const float* src = (i4 < 1048576) ? q : (i4 < 2097152) ? k : v;
    int loc = i4 & 1048575;
    float4 w4 = reinterpret_cast<const float4*>(src)[loc];
    u32 lo = (u32)f2bf(w4.x) | ((u32)f2bf(w4.y) << 16);
    u32 hi = (u32)f2bf(w4.z) | ((u32)f2bf(w4.w) << 16);
    reinterpret_cast<uint2*>(X)[i4] = make_uint2(lo, hi);
    return;
  }
  // gemm_w2 segment (proven body)
  const int xcd = bid & 7, local = bid >> 3;    // 64 per XCD
  const int z = local >> 5;                     // 0..1
  const int mt = xcd * 2 + ((local >> 4) & 1);  // 0..15
  const int nt = local & 15;                    // 0..15
  const u16* Bt = z ? Bt1 : Bt0;
  u16* C = z ? C1 : C0;
  const int w = t >> 6, l = t & 63;
  const int l15 = l & 15, l4 = l >> 4;
  const int m0 = mt * 64, n0 = nt * 64;
  f32x4 acc[4] = {};
  const int row0 = t >> 3, cs0 = t & 7;
  const int c0 = cs0 ^ (row0 & 7);
  const int row1 = row0 + 32;
  const int c1 = cs0 ^ (row1 & 7);
  const u16* gA0 = A + (size_t)(m0 + row0) * 1024 + c0 * 8;
  const u16* gA1 = A + (size_t)(m0 + row1) * 1024 + c1 * 8;
  const u16* gB0 = Bt + (size_t)(n0 + row0) * 1024 + c0 * 8;
  const u16* gB1 = Bt + (size_t)(n0 + row1) * 1024 + c1 * 8;
#define W2_STAGE(KK, DST)                             \
  gload_lds16(gA0 + (KK), &As[DST][0] + w * 512);     \
  gload_lds16(gA1 + (KK), &As[DST][2048] + w * 512);  \
  gload_lds16(gB0 + (KK), &Bs[DST][0] + w * 512);     \
  gload_lds16(gB1 + (KK), &Bs[DST][2048] + w * 512);
  W2_STAGE(0, 0)
  for (int step = 0; step < 16; ++step) {
    const int c = step & 1;
    __syncthreads();
    if (step < 15) { W2_STAGE((step + 1) * 64, c ^ 1) }
#pragma unroll
    for (int ks = 0; ks < 2; ++ks) {
      const int cc = ks * 4 + l4;
      short8 bfr = *reinterpret_cast<const short8*>(&Bs[c][(w * 16 + l15) * 64 + ((cc ^ (l15 & 7)) * 8)]);
#pragma unroll
      for (int i = 0; i < 4; ++i) {
        short8 afr = *reinterpret_cast<const short8*>(&As[c][(i * 16 + l15) * 64 + ((cc ^ (l15 & 7)) * 8)]);
        acc[i] = MFMA16(afr, bfr, acc[i]);
      }
    }
  }
#pragma unroll
  for (int i = 0; i < 4; ++i)
#pragma unroll
    for (int j = 0; j < 4; ++j)
      C[(size_t)(m0 + i * 16 + l4 * 4 + j) * 1024 + n0 + w * 16 + l15] = f2bf(acc[i][j]);
}

// ---------------- fused projection, dbuf, XCD-swizzled (flat 768) ----------------
// seg = mt>>5: 0: Qh=q@(s*Win)^T+s*Win_b ; 1: Kproj=k@Wc2^T+bias2 ; 2: VT=(v@Wc2^T+bias2)^T
// LDS chunk swizzle: physical chunk cs at row r holds data chunk cs^((r>>1)&3)
__global__ __launch_bounds__(256) void proj(const u16* __restrict__ X,
                                            const u16* __restrict__ Winb,
                                            const u16* __restrict__ Wc2,
                                            const float* __restrict__ bias1f,
                                            const float* __restrict__ bias2,
                                            u16* __restrict__ Qh,
                                            u16* __restrict__ Kp,
                                            u16* __restrict__ VT) {
  __shared__ __align__(16) u16 As[2][4096];
  __shared__ __align__(16) u16 Bs[2][4096];
  const int t = threadIdx.x, w = t >> 6, l = t & 63;
  const int l15 = l & 15, l4 = l >> 4;
  const int bid = blockIdx.x;
  const int xcd = bid & 7, local = bid >> 3;  // 96 per XCD
  const int mt = xcd * 12 + (local >> 3);     // 0..95
  const int nt = local & 7;                   // 0..7
  const int seg = mt >> 5;
  const int m0 = mt * 128;
  const int n0 = nt * 128;
  const int wr = (w >> 1) * 64, wc = (w & 1) * 64;
  const u16* Bt = seg == 0 ? Winb : Wc2;
  const float* bias = seg == 0 ? bias1f : bias2;

  f32x4 acc[4][4] = {};
  const int srow = t >> 2;
  const int sck = (t & 3) ^ ((t >> 3) & 3);
  const u16* gA = X + (size_t)(m0 + srow) * 1024 + sck * 8;
  const u16* gB = Bt + (size_t)(n0 + srow) * 1024 + sck * 8;
#define PJ_STAGE(KK, DST)                                   \
  gload_lds16(gA + (KK), &As[DST][0] + w * 512);            \
  gload_lds16(gA + (KK) + 65536, &As[DST][2048] + w * 512); \
  gload_lds16(gB + (KK), &Bs[DST][0] + w * 512);            \
  gload_lds16(gB + (KK) + 65536, &Bs[DST][2048] + w * 512);
  PJ_STAGE(0, 0)
  const int sw = (l15 >> 1) & 3;  // = (row>>1)&3 for rows wr/wc + i*16 + l15
  for (int step = 0; step < 32; ++step) {
    const int c = step & 1;
    __syncthreads();
    if (step < 31) { PJ_STAGE((step + 1) * 32, c ^ 1) }
    short8 af[4], bf[4];
#pragma unroll
    for (int i = 0; i < 4; ++i)
      af[i] = *reinterpret_cast<const short8*>(&As[c][(wr + i * 16 + l15) * 32 + ((l4 ^ sw) * 8)]);
#pragma unroll
    for (int i = 0; i < 4; ++i)
      bf[i] = *reinterpret_cast<const short8*>(&Bs[c][(wc + i * 16 + l15) * 32 + ((l4 ^ sw) * 8)]);
#pragma unroll
    for (int mi = 0; mi < 4; ++mi)
#pragma unroll
      for (int ni = 0; ni < 4; ++ni)
        acc[mi][ni] = MFMA16(af[mi], bf[ni], acc[mi][ni]);
  }

#pragma unroll
  for (int mi = 0; mi < 4; ++mi) {
#pragma unroll
    for (int ni = 0; ni < 4; ++ni) {
      const int col = n0 + wc + ni * 16 + l15;
      const float bv = bias[col];
      const int row0 = m0 + wr + mi * 16 + l4 * 4;
      if (seg == 0) {
#pragma unroll
        for (int j = 0; j < 4; ++j)
          Qh[(size_t)(row0 + j) * 1024 + col] = f2bf(acc[mi][ni][j] + bv);
      } else if (seg == 1) {
#pragma unroll
        for (int j = 0; j < 4; ++j)
          Kp[(size_t)(row0 - 4096 + j) * 1024 + col] = f2bf(acc[mi][ni][j] + bv);
      } else {
        const int r = row0 - 8192;
        const int bb = r >> 11;
        const int sk = r & 2047;
        u32 p0 = (u32)f2bf(acc[mi][ni][0] + bv) | ((u32)f2bf(acc[mi][ni][1] + bv) << 16);
        u32 p1 = (u32)f2bf(acc[mi][ni][2] + bv) | ((u32)f2bf(acc[mi][ni][3] + bv) << 16);
        *reinterpret_cast<uint2*>(VT + ((size_t)(bb * 1024 + col)) * 2048 + sk) = make_uint2(p0, p1);
      }
    }
  }
}

// ---------------- fused masked attention: swapped QK^T, in-register P (proven) ----------------
// flat 640: blocks [0,512) attn (bh=(bid&7)*4+((bid>>3)&3), qb=bid>>5);
//           blocks [512,640) compute bias3 = Wout_w@Wff_b + Wout_b (8 rows/block, 8 waves)
__global__ __launch_bounds__(512) void attn(const u16* __restrict__ Qh,
                                            const u16* __restrict__ Kb,
                                            const u16* __restrict__ VT,
                                            const int* __restrict__ mask,
                                            u16* __restrict__ AO,
                                            const float* __restrict__ Wout_w,
                                            const float* __restrict__ Wff_b,
                                            const float* __restrict__ Wout_b,
                                            float* __restrict__ bias3) {
  __shared__ __align__(16) u16 Kt[128 * 64];    // [key 0..127][dh], pre-swizzled 16B chunks
  __shared__ __align__(16) u16 Vt[2][64 * 64];  // [half][dh][pos], 128B pitch (2-way free)
  __shared__ float biasS[2048];
  const int t = threadIdx.x, l = t & 63, w = t >> 6;
  const int bid = blockIdx.x;

  if (bid >= 512) {  // bias3 blocks (block-uniform branch)
    const int j = (bid - 512) * 8 + w;
    const float4* Wr = reinterpret_cast<const float4*>(Wout_w + (size_t)j * 1024);
    const float4* br = reinterpret_cast<const float4*>(Wff_b);
    float s = 0.f;
    for (int i = l; i < 256; i += 64) {
      float4 a = Wr[i], b = br[i];
      s += a.x * b.x + a.y * b.y + a.z * b.z + a.w * b.w;
    }
#pragma unroll
    for (int o = 1; o < 64; o <<= 1) s += __shfl_xor(s, o);
    if (l == 0) bias3[j] = s + Wout_b[j];
    return;
  }

  const int l15 = l & 15, l4 = l >> 4;
  const int bh = (bid & 7) * 4 + ((bid >> 3) & 3);
  const int qb = bid >> 5;
  const int b = bh >> 4, h = bh & 15, q0 = qb * 128;

  for (int i = t; i < 2048; i += 512) biasS[i] = mask[b * 2048 + i] ? 0.f : -1.442695e9f;

  short8 qf[2];
  {
    const u16* qp = Qh + (size_t)(b * 2048 + q0 + w * 16 + l15) * 1024 + h * 64 + l4 * 8;
    qf[0] = *reinterpret_cast<const short8*>(qp);
    qf[1] = *reinterpret_cast<const short8*>(qp + 32);
  }
  short8 ones;
#pragma unroll
  for (int i = 0; i < 8; ++i) ones[i] = (short)0x3F80;  // bf16 1.0

  f32x4 acc[4] = {};
  f32x4 accS = {};  // denominator accumulator (every lane ends with its row's sum)

  const int rr = t >> 3, cs = t & 7;   // rr 0..63: K rows rr,rr+64; V d-row rr
  const int ck = cs ^ (rr & 7);        // data chunk stored at this thread's physical slot
  const int vb = (ck >> 2) * 32 + (ck & 3) * 4;
  const u16* gK = Kb + (size_t)(b * 2048 + rr) * 1024 + h * 64 + ck * 8;
  u16* ldsK = Kt + w * 512;            // wave base; 2nd gload at +4096 (rows 64..127)
  const u32* gVrow = reinterpret_cast<const u32*>(VT) + (size_t)(b * 1024 + h * 64 + rr) * 1024;

  for (int kt = 0; kt < 2048; kt += 128) {
    const int ia = (kt >> 1) + (vb >> 1);
    uint2 a01 = *reinterpret_cast<const uint2*>(gVrow + ia);
    uint2 a89 = *reinterpret_cast<const uint2*>(gVrow + ia + 8);
    uint2 b01 = *reinterpret_cast<const uint2*>(gVrow + ia + 32);
    uint2 b89 = *reinterpret_cast<const uint2*>(gVrow + ia + 40);
    __syncthreads();  // barrier1: all waves done reading Kt/Vt of previous stage
    gload_lds16(gK + (size_t)kt * 1024, ldsK);
    gload_lds16(gK + (size_t)(kt + 64) * 1024, ldsK + 4096);
    *reinterpret_cast<uint4*>(&Vt[0][rr * 64 + cs * 8]) = make_uint4(a01.x, a01.y, a89.x, a89.y);
    *reinterpret_cast<uint4*>(&Vt[1][rr * 64 + cs * 8]) = make_uint4(b01.x, b01.y, b89.x, b89.y);
    __syncthreads();  // barrier2: staging visible (vmcnt+lgkm drained)

#pragma unroll
    for (int half = 0; half < 2; ++half) {
      const int kb0 = kt + half * 64;
      f32x4 s[4];
#pragma unroll
      for (int n = 0; n < 4; ++n)
        s[n] = *reinterpret_cast<const f32x4*>(&biasS[kb0 + n * 16 + l4 * 4]);
      __builtin_amdgcn_s_setprio(1);
#pragma unroll
      for (int ks = 0; ks < 2; ++ks) {
        const int cc = ks * 4 + l4;
#pragma unroll
        for (int n = 0; n < 4; ++n) {
          short8 kb = *reinterpret_cast<const short8*>(
              &Kt[(half * 64 + n * 16 + l15) * 64 + ((cc ^ (l15 & 7)) * 8)]);
          s[n] = MFMA16(kb, qf[ks], s[n]);
        }
      }
      __builtin_amdgcn_s_setprio(0);
#pragma unroll
      for (int n = 0; n < 4; ++n)
#pragma unroll
        for (int j = 0; j < 4; ++j) s[n][j] = __builtin_amdgcn_exp2f(s[n][j]);
      u32 paw[8];
      paw[0] = pack_bf16(s[0][0], s[0][1]);
      paw[1] = pack_bf16(s[0][2], s[0][3]);
      paw[2] = pack_bf16(s[1][0], s[1][1]);
      paw[3] = pack_bf16(s[1][2], s[1][3]);
      paw[4] = pack_bf16(s[2][0], s[2][1]);
      paw[5] = pack_bf16(s[2][2], s[2][3]);
      paw[6] = pack_bf16(s[3][0], s[3][1]);
      paw[7] = pack_bf16(s[3][2], s[3][3]);
      const short8 pa0 = *reinterpret_cast<const short8*>(&paw[0]);
      const short8 pa1 = *reinterpret_cast<const short8*>(&paw[4]);
      __builtin_amdgcn_s_setprio(1);
#pragma unroll
      for (int ks = 0; ks < 2; ++ks) {
        const short8 pa = ks ? pa1 : pa0;
        const int cc = ks * 4 + l4;
#pragma unroll
        for (int n = 0; n < 4; ++n) {
          short8 vb8 = *reinterpret_cast<const short8*>(
              &Vt[half][(n * 16 + l15) * 64 + ((cc ^ (l15 & 7)) * 8)]);
          acc[n] = MFMA16(pa, vb8, acc[n]);
        }
        accS = MFMA16(pa, ones, accS);
      }
      __builtin_amdgcn_s_setprio(0);
    }
  }

  const size_t orow0 = (size_t)(b * 2048 + q0 + w * 16 + l4 * 4);
#pragma unroll
  for (int j = 0; j < 4; ++j) {
    const float inv = 1.0f / accS[j];
#pragma unroll
    for (int n = 0; n < 4; ++n)
      AO[(orow0 + j) * 1024 + h * 64 + n * 16 + l15] = f2bf(acc[n][j] * inv);
  }
}

// ---------------- tail GEMM: out = AO @ Wc3^T + bias3 (f32), dbuf, XCD-swizzled flat 512 ----------------
__global__ __launch_bounds__(256) void gemm_tail(const u16* __restrict__ A,
                                                 const u16* __restrict__ Bt,
                                                 const float* __restrict__ bias,
                                                 float* __restrict__ C) {
  __shared__ __align__(16) u16 As[2][4096];
  __shared__ __align__(16) u16 Bs[2][2048];
  const int t = threadIdx.x, w = t >> 6, l = t & 63;
  const int l15 = l & 15, l4 = l >> 4;
  const int bid = blockIdx.x;
  const int xcd = bid & 7, local = bid >> 3;  // 64 per XCD
  const int mt = xcd * 4 + (local >> 4);      // 0..31
  const int nt = local & 15;                  // 0..15
  const int m0 = mt * 128, n0 = nt * 64;
  const int wr = (w >> 1) * 64, wc = (w & 1) * 32;
  f32x4 acc[4][2] = {};
  const int srow = t >> 2;
  const int sck = (t & 3) ^ ((t >> 3) & 3);
  const u16* gA = A + (size_t)(m0 + srow) * 1024 + sck * 8;
  const u16* gB = Bt + (size_t)(n0 + srow) * 1024 + sck * 8;
#define TL_STAGE(KK, DST)                                   \
  gload_lds16(gA + (KK), &As[DST][0] + w * 512);            \
  gload_lds16(gA + (KK) + 65536, &As[DST][2048] + w * 512); \
  gload_lds16(gB + (KK), &Bs[DST][0] + w * 512);
  TL_STAGE(0, 0)
  const int sw = (l15 >> 1) & 3;
  for (int step = 0; step < 32; ++step) {
    const int c = step & 1;
    __syncthreads();
    if (step < 31) { TL_STAGE((step + 1) * 32, c ^ 1) }
    short8 af[4], bf[2];
#pragma unroll
    for (int i = 0; i < 4; ++i)
      af[i] = *reinterpret_cast<const short8*>(&As[c][(wr + i * 16 + l15) * 32 + ((l4 ^ sw) * 8)]);
#pragma unroll
    for (int i = 0; i < 2; ++i)
      bf[i] = *reinterpret_cast<const short8*>(&Bs[c][(wc + i * 16 + l15) * 32 + ((l4 ^ sw) * 8)]);
#pragma unroll
    for (int mi = 0; mi < 4; ++mi)
#pragma unroll
      for (int ni = 0; ni < 2; ++ni)
        acc[mi][ni] = MFMA16(af[mi], bf[ni], acc[mi][ni]);
  }
#pragma unroll
  for (int mi = 0; mi < 4; ++mi) {
#pragma unroll
    for (int ni = 0; ni < 2; ++ni) {
      const int col = n0 + wc + ni * 16 + l15;
      const float bv = bias[col];
      const int row0 = m0 + wr + mi * 16 + l4 * 4;
#pragma unroll
      for (int j = 0; j < 4; ++j)
        C[(size_t)(row0 + j) * 1024 + col] = acc[mi][ni][j] + bv;
    }
  }
}

// ---------------- launcher ----------------
// ws layout (peak 56,623,104 B, proven):
//   [ 0,24) MB  Xbf (q/k/v bf16 12288x1024); AO = [0,8) after proj; bias3 @ 20 MB after proj
//   [24,32) MB  Qh ; phase-A tenants: WinT@24, Woutb@26, WffT@28
//   [32,40) MB  Kproj
//   [40,48) MB  VT
//   [48,50) MB  Wc2 ; [50,52) Wc3 ; [52,54) Winb
//   bias2 = d_out[0:1024], bias1f = d_out[1024:2048] (dead until tail overwrites all of out)
extern "C" void kernel_launch(void* const* d_in, const int* in_sizes, int n_in,
                              void* d_out, int out_size, void* d_ws, size_t ws_size,
                              hipStream_t stream) {
  const float* q = (const float*)d_in[0];
  const float* k = (const float*)d_in[1];
  const float* v = (const float*)d_in[2];
  const float* Win_w = (const float*)d_in[3];
  const float* Win_b = (const float*)d_in[4];
  const float* Wff_w = (const float*)d_in[5];
  const float* Wff_b = (const float*)d_in[6];
  const float* Wout_w = (const float*)d_in[7];
  const float* Wout_b = (const float*)d_in[8];
  const int* mask = (const int*)d_in[9];
  float* out = (float*)d_out;

  char* ws = (char*)d_ws;
  u16* Xbf = (u16*)ws;
  u16* AO = (u16*)ws;
  float* bias3 = (float*)(ws + 20971520);
  u16* Qh = (u16*)(ws + 25165824);
  u16* WinT = (u16*)(ws + 25165824);
  u16* Woutb = (u16*)(ws + 27262976);
  u16* WffT = (u16*)(ws + 29360128);
  u16* Kproj = (u16*)(ws + 33554432);
  u16* VT = (u16*)(ws + 41943040);
  u16* Wc2 = (u16*)(ws + 50331648);
  u16* Wc3 = (u16*)(ws + 52428800);
  u16* Winb = (u16*)(ws + 54525952);
  float* bias2 = out;
  float* bias1f = out + 1024;

  prep_w<<<2817, 256, 0, stream>>>(Wout_w, Win_w, Wff_w, Win_b, Wout_b,
                                   Woutb, Winb, WinT, WffT, bias2, bias1f);
  w2_cvt<<<12800, 256, 0, stream>>>(Woutb, WinT, WffT, Wc2, Wc3, q, k, v, Xbf);
  proj<<<768, 256, 0, stream>>>(Xbf, Winb, Wc2, bias1f, bias2, Qh, Kproj, VT);
  attn<<<640, 512, 0, stream>>>(Qh, Kproj, VT, mask, AO, Wout_w, Wff_b, Wout_b, bias3);
  gemm_tail<<<512, 256, 0, stream>>>(AO, Wc3, bias3, out);
}